// Round 16
// baseline (17029.219 us; speedup 1.0000x reference)
//
#include <hip/hip_runtime.h>

// ---------------------------------------------------------------------------
// DeepMemoryLevel (ATLAS-style). B=2 S=1024 D=2048 M=512 P=1024 H=2048
// CHUNK=32 NC=32, tokens N=2048.
// Round 16: R15 + (a) symmetric NS square GEMMs — compute diag+upper tiles
// only (36/64) and mirror-write the lower triangle from LDS (bit-exact);
// (b) G5+G6 merged into one launch; (c) wtrans pair merged into one launch.
// ---------------------------------------------------------------------------

typedef unsigned short us;
typedef __attribute__((ext_vector_type(8))) short s16x8;
typedef __attribute__((ext_vector_type(8))) unsigned short u16x8;
typedef __attribute__((ext_vector_type(4))) float f32x4;

#define MKP 72

__device__ __forceinline__ float gelu_f(float x) {
  return 0.5f * x * (1.0f + erff(x * 0.70710678118654752f));
}
__device__ __forceinline__ float gelu_grad_f(float x) {
  float cdf = 0.5f * (1.0f + erff(x * 0.70710678118654752f));
  float pdf = 0.3989422804014327f * expf(-0.5f * x * x);
  return cdf + x * pdf;
}
__device__ __forceinline__ float sigmoid_f(float x) { return 1.0f / (1.0f + expf(-x)); }

__device__ __forceinline__ us f2bf(float f) {
  union { float f; unsigned u; } v; v.f = f;
  unsigned r = (v.u + 0x7FFFu + ((v.u >> 16) & 1u)) >> 16;
  return (us)r;
}
__device__ __forceinline__ float bf2f(us h) {
  union { unsigned u; float f; } v; v.u = ((unsigned)h) << 16;
  return v.f;
}
// token-major index n -> chunk-major row
__device__ __forceinline__ int cm_map(int n) {
  return ((n & 1023) >> 5) * 64 + (n >> 10) * 32 + (n & 31);
}
// packed-fragment offset: matrix R x K (row-major source), element (r,k).
__device__ __forceinline__ size_t pf_off(int r, int k, int KB) {
  return ((size_t)(r >> 4) * KB + (k >> 5)) * 512 + ((k >> 3) & 3) * 128 + (r & 15) * 8 + (k & 7);
}

__device__ __forceinline__ float block_reduce_sum(float v, float* red) {
  int t = threadIdx.x;
  red[t] = v; __syncthreads();
  for (int s = blockDim.x >> 1; s > 0; s >>= 1) {
    if (t < s) red[t] += red[t + s];
    __syncthreads();
  }
  float r = red[0];
  __syncthreads();
  return r;
}

// ---------------- packed-fragment GEMM core (R12-proven) ----------------
__device__ __forceinline__ void gemm_pk(const us* __restrict__ A,
                                        const us* __restrict__ B, int KB,
                                        int lane, int m0, int n0,
                                        f32x4 (&acc)[4][4]) {
  const us* am[4];
  const us* bm[4];
#pragma unroll
  for (int q = 0; q < 4; ++q) {
    am[q] = A + (size_t)((m0 >> 4) + q) * KB * 512 + lane * 8;
    bm[q] = B + (size_t)((n0 >> 4) + q) * KB * 512 + lane * 8;
  }
#pragma unroll
  for (int i = 0; i < 4; ++i)
#pragma unroll
    for (int j = 0; j < 4; ++j) acc[i][j] = (f32x4){0.f, 0.f, 0.f, 0.f};
  u16x8 a0[4], b0[4], a1[4], b1[4];
#pragma unroll
  for (int q = 0; q < 4; ++q) {
    a0[q] = *(const u16x8*)(am[q]);
    b0[q] = *(const u16x8*)(bm[q]);
    a1[q] = *(const u16x8*)(am[q] + 512);
    b1[q] = *(const u16x8*)(bm[q] + 512);
  }
  for (int kb = 0; kb < KB; kb += 2) {
#pragma unroll
    for (int mi = 0; mi < 4; ++mi)
#pragma unroll
      for (int ni = 0; ni < 4; ++ni)
        acc[mi][ni] = __builtin_amdgcn_mfma_f32_16x16x32_bf16(
            (s16x8)a0[mi], (s16x8)b0[ni], acc[mi][ni], 0, 0, 0);
    if (kb + 2 < KB) {
#pragma unroll
      for (int q = 0; q < 4; ++q) {
        a0[q] = *(const u16x8*)(am[q] + (size_t)(kb + 2) * 512);
        b0[q] = *(const u16x8*)(bm[q] + (size_t)(kb + 2) * 512);
      }
    }
#pragma unroll
    for (int mi = 0; mi < 4; ++mi)
#pragma unroll
      for (int ni = 0; ni < 4; ++ni)
        acc[mi][ni] = __builtin_amdgcn_mfma_f32_16x16x32_bf16(
            (s16x8)a1[mi], (s16x8)b1[ni], acc[mi][ni], 0, 0, 0);
    if (kb + 3 < KB) {
#pragma unroll
      for (int q = 0; q < 4; ++q) {
        a1[q] = *(const u16x8*)(am[q] + (size_t)(kb + 3) * 512);
        b1[q] = *(const u16x8*)(bm[q] + (size_t)(kb + 3) * 512);
      }
    }
  }
}

// ---------------- 4-wave 128x128 packed MFMA GEMM (barrier-free) ----------
// TRI=1: only diag+upper tiles computed (M=N=1024, 8x8 tile space -> 36
// tiles/batch); off-diag tiles mirror-write the transposed block (bit-exact).
// EPI 20: C packed (KC = N>>5).
// EPI 21: C packed = c1*acc + c2*E_packed (same layout).
// EPI 23: X-update it<4: o = acc + c1*E(XPc packed KB=64);
//         C=XPn packed (KB=64), C2=XTPn packed ([2048][1024], KB=32).
// EPI 24: X-update it=4: o = acc + c1*E(packed KB=64); C row-major ldc=2048.
template<int EPI, int TRI, int TM, int TN>
__global__ __launch_bounds__(256)
void mgp_k(const us* __restrict__ Aq, const us* __restrict__ Bq,
           us* __restrict__ Cq, us* __restrict__ C2q, const us* __restrict__ Eq,
           int K, int N, float c1, float c2,
           long sA, long sB, long sC, long sE) {
  __shared__ __align__(16) us ct[4 * 64 * 72];
  const int tid = threadIdx.x;
  const int wave = tid >> 6, lane = tid & 63;
  const int l15 = lane & 15, l4 = lane >> 4;
  const int wm = (wave >> 1) * 64, wn = (wave & 1) * 64;
  int bz, m0, n0;
  bool mir = false;
  if constexpr (TRI) {
    const int per = TM * (TM + 1) / 2;
    int t = blockIdx.x;
    bz = t / per;
    int ti = t - bz * per;
    int m0t, n0t;
    if (ti < TM) { m0t = n0t = ti * 128; }
    else {
      int p = ti - TM, i = 0;
      while (p >= TM - 1 - i) { p -= TM - 1 - i; ++i; }
      m0t = i * 128; n0t = (i + 1 + p) * 128; mir = true;
    }
    m0 = m0t + wm; n0 = n0t + wn;
  } else {
    const int TPB = TM * TN;
    int t = blockIdx.x;
    bz = t / TPB;
    int ti = t - bz * TPB;
    m0 = (ti / TN) * 128 + wm;
    n0 = (ti % TN) * 128 + wn;
  }

  const us* A = Aq + (size_t)bz * sA;
  const us* B = Bq + (size_t)bz * sB;
  us* C = Cq + (size_t)bz * sC;
  us* C2 = C2q + (size_t)bz * sC;
  const us* E = Eq + (size_t)bz * sE;
  const int KB = K >> 5;

  f32x4 acc[4][4];
  gemm_pk(A, B, KB, lane, m0, n0, acc);

  us* cw = ct + wave * 64 * 72;
  // stage quadrant into per-wave LDS slice (1 wave: in-order DS, no barrier)
#pragma unroll
  for (int mi = 0; mi < 4; ++mi)
#pragma unroll
    for (int i = 0; i < 4; ++i)
#pragma unroll
      for (int ni = 0; ni < 4; ++ni)
        cw[(mi * 16 + l4 * 4 + i) * 72 + ni * 16 + l15] = f2bf(acc[mi][ni][i]);

  if constexpr (EPI == 20 || EPI == 21) {
    const int KC = N >> 5;
#pragma unroll
    for (int q = 0; q < 8; ++q) {
      u16x8 v = *(const u16x8*)&cw[lane * 72 + q * 8];
      size_t off = pf_off(m0 + lane, n0 + q * 8, KC);
      if constexpr (EPI == 21) {
        u16x8 e = *(const u16x8*)(E + off);
        u16x8 o;
#pragma unroll
        for (int w = 0; w < 8; ++w) o[w] = f2bf(c1 * bf2f(v[w]) + c2 * bf2f(e[w]));
        *(u16x8*)(C + off) = o;
      } else {
        *(u16x8*)(C + off) = v;
      }
    }
    if (TRI && mir) {
      // mirror block (n0,m0): transposed read of cw, bit-exact copy
#pragma unroll
      for (int q = 0; q < 8; ++q) {
        u16x8 vT;
#pragma unroll
        for (int w = 0; w < 8; ++w) vT[w] = cw[(q * 8 + w) * 72 + lane];
        size_t offM = pf_off(n0 + lane, m0 + q * 8, KC);
        if constexpr (EPI == 21) {
          u16x8 e = *(const u16x8*)(E + offM);
          u16x8 o;
#pragma unroll
          for (int w = 0; w < 8; ++w) o[w] = f2bf(c1 * bf2f(vT[w]) + c2 * bf2f(e[w]));
          *(u16x8*)(C + offM) = o;
        } else {
          *(u16x8*)(C + offM) = vT;
        }
      }
    }
  } else if constexpr (EPI == 23) {
    // combine with c1*E (E = Xc packed, KB=64), write XPn; update cw in place
#pragma unroll
    for (int q = 0; q < 8; ++q) {
      size_t off = pf_off(m0 + lane, n0 + q * 8, 64);
      u16x8 v = *(const u16x8*)&cw[lane * 72 + q * 8];
      u16x8 e = *(const u16x8*)(E + off);
      u16x8 o;
#pragma unroll
      for (int w = 0; w < 8; ++w) o[w] = f2bf(bf2f(v[w]) + c1 * bf2f(e[w]));
      *(u16x8*)&cw[lane * 72 + q * 8] = o;
      *(u16x8*)(C + off) = o;
    }
    // packed transpose out: XT[2048][1024], KB=32 (same-wave DS ordering safe)
#pragma unroll
    for (int q = 0; q < 8; ++q) {
      u16x8 o;
#pragma unroll
      for (int w = 0; w < 8; ++w) o[w] = cw[(q * 8 + w) * 72 + lane];
      size_t offT = pf_off(n0 + lane, m0 + q * 8, 32);
      *(u16x8*)(C2 + offT) = o;
    }
  } else {  // EPI 24: row-major out [1024][2048], combine with c1*E packed
#pragma unroll
    for (int q = 0; q < 8; ++q) {
      size_t off = pf_off(m0 + lane, n0 + q * 8, 64);
      u16x8 v = *(const u16x8*)&cw[lane * 72 + q * 8];
      u16x8 e = *(const u16x8*)(E + off);
      u16x8 o;
#pragma unroll
      for (int w = 0; w < 8; ++w) o[w] = f2bf(bf2f(v[w]) + c1 * bf2f(e[w]));
      *(u16x8*)(C + (size_t)(m0 + lane) * 2048 + n0 + q * 8) = o;
    }
  }
}

template<int EPI, int TRI, int TM, int TN>
static void mgp(hipStream_t st, const us* A, const us* B, us* C, us* C2,
                const us* E, int K, int N, float c1, float c2,
                long sA, long sB, long sC, long sE) {
  dim3 g(TRI ? TM * (TM + 1) : TM * TN * 2), b(256);
  hipLaunchKernelGGL((mgp_k<EPI, TRI, TM, TN>), g, b, 0, st, A, B, C, C2, E,
                     K, N, c1, c2, sA, sB, sC, sE);
}

// ---------------- epilogue for LDS GEMM (chunk path) ----------------
template<int EPI>
__device__ __forceinline__ void epilogue(f32x4 (&acc)[4][4], int m0, int n0,
    int l15, int l4, void* Cq, void* C2, const void* Eq,
    const float* FX, const float* OG, const float* cp, int cidx,
    int ldc, int lde, float c1, float c2) {
#pragma unroll
  for (int mi = 0; mi < 4; ++mi) {
#pragma unroll
    for (int i = 0; i < 4; ++i) {
      int grow = m0 + mi * 16 + l4 * 4 + i;
#pragma unroll
      for (int ni = 0; ni < 4; ++ni) {
        int col = n0 + ni * 16 + l15;
        float v = acc[mi][ni][i];
        if constexpr (EPI == 5) {
          ((us*)Cq)[(size_t)grow * ldc + col] = f2bf(v);
        } else if constexpr (EPI == 7) {
          ((float*)Cq)[(size_t)grow * ldc + col] = v;
        } else if constexpr (EPI == 8) {
          ((us*)Cq)[(size_t)grow * ldc + col] = f2bf(gelu_f(v));
          if (m0 >= 64)
            ((float*)C2)[(size_t)(grow - 64) * ldc + col] = gelu_grad_f(v);
        } else if constexpr (EPI == 9) {
          if (m0 < 64)
            ((us*)Cq)[(size_t)grow * ldc + col] = f2bf(v);
          else
            ((us*)Cq)[(size_t)grow * ldc + col] =
                f2bf(2.0f * (v - ((const float*)Eq)[(size_t)(grow - 64) * lde + col]));
        } else if constexpr (EPI == 13) {
          ((float*)Cq)[(size_t)grow * ldc + col] =
              v * ((const float*)Eq)[(size_t)grow * lde + col];
        } else if constexpr (EPI == 14) {
          float* C = (float*)Cq;
          float old = C[(size_t)grow * ldc + col];
          C[(size_t)grow * ldc + col] = cp[cidx * 3 + 1] * old - cp[cidx * 3 + 0] * v;
        } else if constexpr (EPI == 15) {
          ((float*)Cq)[(size_t)grow * ldc + col] =
              FX[(size_t)grow * ldc + col] + v * OG[grow];
        } else if constexpr (EPI == 17) {
          int crow = cm_map(grow);
          ((float*)Cq)[(size_t)crow * ldc + col] = v;
        }
      }
    }
  }
}

// ---------------- 1-wave 64x64 LDS GEMM body (chunk path) ----------------
template<int EPI, int TA, int DUAL, int AG>
__device__ __forceinline__ void mg_body(const us* __restrict__ A0,
    const us* __restrict__ A2, const us* __restrict__ B,
    void* __restrict__ Cq, void* __restrict__ C2, const void* __restrict__ Eq,
    const float* __restrict__ FX, const float* __restrict__ OG,
    const float* __restrict__ cp, int cidx, int m0, int n0,
    int K, int lda, int ldb, int ldc, int lde, float c1, float c2,
    us* As, us* Bs, int t) {
  const us* A = A0;
  if constexpr (DUAL) { if (m0 >= 64) A = A2; }
  const int mA0 = DUAL ? (m0 & 63) : m0;
  const int l15 = t & 15, l4 = t >> 4;

  f32x4 acc[4][4];
#pragma unroll
  for (int i = 0; i < 4; ++i)
#pragma unroll
    for (int j = 0; j < 4; ++j) acc[i][j] = (f32x4){0.f, 0.f, 0.f, 0.f};

  const int srw = t >> 3;
  const int sck = (t & 7) * 8;

  u16x8 ra[8], rb[8];
  auto LDA = [&](int k0) {
#pragma unroll
    for (int p = 0; p < 8; ++p) {
      if constexpr (TA == 0) {
        int row = srw + p * 8;
        int srow;
        if constexpr (AG) srow = cm_map(m0 + row); else srow = mA0 + row;
        ra[p] = *(const u16x8*)(A + (size_t)srow * lda + k0 + sck);
      } else {
        ra[p] = *(const u16x8*)(A + (size_t)(k0 + srw + p * 8) * lda + mA0 + sck);
      }
    }
  };
  auto LDB = [&](int k0) {
#pragma unroll
    for (int p = 0; p < 8; ++p)
      rb[p] = *(const u16x8*)(B + (size_t)(n0 + srw + p * 8) * ldb + k0 + sck);
  };

  LDA(0); LDB(0);
  for (int k0 = 0; k0 < K; k0 += 64) {
    if constexpr (TA == 0) {
#pragma unroll
      for (int p = 0; p < 8; ++p)
        *(u16x8*)&As[(srw + p * 8) * MKP + sck] = ra[p];
    } else {
#pragma unroll
      for (int p = 0; p < 8; ++p) {
        int kk = srw + p * 8;
#pragma unroll
        for (int j = 0; j < 8; ++j) As[(sck + j) * MKP + kk] = ra[p][j];
      }
    }
#pragma unroll
    for (int p = 0; p < 8; ++p)
      *(u16x8*)&Bs[(srw + p * 8) * MKP + sck] = rb[p];
    if (k0 + 64 < K) { LDA(k0 + 64); LDB(k0 + 64); }
#pragma unroll
    for (int ks = 0; ks < 2; ++ks) {
      s16x8 af[4], bf[4];
#pragma unroll
      for (int mi = 0; mi < 4; ++mi)
        af[mi] = *(const s16x8*)&As[(mi * 16 + l15) * MKP + ks * 32 + l4 * 8];
#pragma unroll
      for (int ni = 0; ni < 4; ++ni)
        bf[ni] = *(const s16x8*)&Bs[(ni * 16 + l15) * MKP + ks * 32 + l4 * 8];
#pragma unroll
      for (int mi = 0; mi < 4; ++mi)
#pragma unroll
        for (int ni = 0; ni < 4; ++ni)
          acc[mi][ni] = __builtin_amdgcn_mfma_f32_16x16x32_bf16(af[mi], bf[ni], acc[mi][ni], 0, 0, 0);
    }
  }

  epilogue<EPI>(acc, m0, n0, l15, l4, Cq, C2, Eq, FX, OG, cp, cidx,
                ldc, lde, c1, c2);
}

template<int EPI, int TA, int DUAL, int AG>
__global__ __launch_bounds__(64)
void mg_k(const us* __restrict__ Aq, const us* __restrict__ A2,
          const us* __restrict__ Bq, void* __restrict__ Cq,
          void* __restrict__ C2, const void* __restrict__ Eq,
          const float* __restrict__ FX, const float* __restrict__ OG,
          const float* __restrict__ cp, int cidx,
          int M, int N, int K, int lda, int ldb, int ldc, int lde,
          float c1, float c2) {
  __shared__ __align__(16) us As[64 * MKP];
  __shared__ __align__(16) us Bs[64 * MKP];
  mg_body<EPI, TA, DUAL, AG>(Aq, A2, Bq, Cq, C2, Eq, FX, OG, cp, cidx,
                             blockIdx.y * 64, blockIdx.x * 64, K, lda, ldb,
                             ldc, lde, c1, c2, As, Bs, threadIdx.x);
}

template<int EPI, int TA = 0, int DUAL = 0, int AG = 0>
static void mg(hipStream_t st, const us* A, const us* A2, const us* B,
               void* C, void* C2, const void* E,
               const float* FX, const float* OG, const float* cp, int cidx,
               int M, int N, int K, int lda, int ldb, int ldc, int lde,
               float c1 = 0.f, float c2 = 0.f) {
  dim3 g(N / 64, M / 64, 1), b(64);
  hipLaunchKernelGGL((mg_k<EPI, TA, DUAL, AG>), g, b, 0, st, A, A2, B, C, C2, E,
                     FX, OG, cp, cidx, M, N, K, lda, ldb, ldc, lde, c1, c2);
}

// ---------------- merged G5+G6 (EPI 14, TA=1): 1024 blocks 1D ----------------
__global__ __launch_bounds__(64)
void mg2_k(const us* __restrict__ kp_c, const us* __restrict__ dhT,
           float* __restrict__ S0, const us* __restrict__ habk,
           const us* __restrict__ rbwT, float* __restrict__ S1,
           const float* __restrict__ cp, int c) {
  __shared__ __align__(16) us As[64 * MKP];
  __shared__ __align__(16) us Bs[64 * MKP];
  int bid = blockIdx.x;
  if (bid < 512) {
    int m0 = (bid >> 5) * 64, n0 = (bid & 31) * 64;   // M=1024, N=2048
    mg_body<14, 1, 0, 0>(kp_c, nullptr, dhT, S0, nullptr, nullptr,
                         nullptr, nullptr, cp, c, m0, n0,
                         64, 1024, 64, 2048, 0, 0.f, 0.f, As, Bs, threadIdx.x);
  } else {
    int b2 = bid - 512;
    int m0 = (b2 >> 4) * 64, n0 = (b2 & 15) * 64;     // M=2048, N=1024
    mg_body<14, 1, 0, 0>(habk, nullptr, rbwT, S1, nullptr, nullptr,
                         nullptr, nullptr, cp, c, m0, n0,
                         64, 2048, 64, 1024, 0, 0.f, 0.f, As, Bs, threadIdx.x);
  }
}

// ---------------- merged wtrans pair: 192 blocks 1D, block (32,8) -----------
__global__ void wt2_k(const float* __restrict__ dh, const float* __restrict__ w0inv,
                      us* __restrict__ dhT, const us* __restrict__ prg,
                      const float* __restrict__ w1inv, us* __restrict__ rbwT) {
  __shared__ float tile[32][33];
  int bid = blockIdx.x;
  int tx = threadIdx.x, ty = threadIdx.y;
  int c0, r0, ldin;
  const float* wv;
  us* outp;
  bool f32in;
  const void* in;
  if (bid < 128) {
    in = dh; wv = w0inv; outp = dhT; ldin = 2048; f32in = true;
    c0 = (bid & 63) * 32; r0 = (bid >> 6) * 32;
  } else {
    int b2 = bid - 128;
    in = prg; wv = w1inv; outp = rbwT; ldin = 1024; f32in = false;
    c0 = (b2 & 31) * 32; r0 = (b2 >> 5) * 32;
  }
#pragma unroll
  for (int j = 0; j < 4; ++j) {
    int r = r0 + ty + 8 * j, cc = c0 + tx;
    float v = f32in ? ((const float*)in)[(size_t)r * ldin + cc]
                    : bf2f(((const us*)in)[(size_t)r * ldin + cc]);
    tile[ty + 8 * j][tx] = v * wv[r];
  }
  __syncthreads();
#pragma unroll
  for (int j = 0; j < 4; ++j)
    outp[(size_t)(c0 + ty + 8 * j) * 64 + r0 + tx] = f2bf(tile[tx][ty + 8 * j]);
}

// ---------------- scale + pack (merged, z=2): S -> XP + XTP packed -----------
__global__ void scalepk2_k(const float* __restrict__ S0, const float* __restrict__ S1,
                           const float* __restrict__ inv01,
                           us* __restrict__ XP, us* __restrict__ XTP) {
  __shared__ float tile[32][33];
  const long SB2c = 2097152;
  int z = blockIdx.z;
  float s = inv01[z];
  int tx = threadIdx.x, ty = threadIdx.y;  // 32 x 8
  int r0, c0;
  const float* S;
  if (z == 0) { S = S0; c0 = blockIdx.x * 32; r0 = blockIdx.y * 32; }
  else        { S = S1; r0 = blockIdx.x * 32; c0 = blockIdx.y * 32; }
  int C = (z == 0) ? 2048 : 1024;
#pragma unroll
  for (int j = 0; j < 4; ++j)
    tile[ty + 8 * j][tx] = S[(size_t)(r0 + ty + 8 * j) * C + c0 + tx] * s;
  __syncthreads();
  us* xp = XP + (size_t)z * SB2c;
  us* xt = XTP + (size_t)z * SB2c;
  int t = ty * 32 + tx;
  if (t < 128) {
    int rh = t >> 2, cc = t & 3;
    u16x8 v;
#pragma unroll
    for (int e = 0; e < 8; ++e) v[e] = f2bf(tile[rh][cc * 8 + e]);
    if (z == 0) {
      *(u16x8*)(xp + pf_off(r0 + rh, c0 + cc * 8, 64)) = v;
    } else {
      *(u16x8*)(xt + pf_off(r0 + rh, c0 + cc * 8, 32)) = v;
    }
  } else {
    int ch = (t - 128) >> 2, rc = (t - 128) & 3;
    u16x8 v;
#pragma unroll
    for (int e = 0; e < 8; ++e) v[e] = f2bf(tile[rc * 8 + e][ch]);
    if (z == 0) {
      *(u16x8*)(xt + pf_off(c0 + ch, r0 + rc * 8, 32)) = v;
    } else {
      *(u16x8*)(xp + pf_off(c0 + ch, r0 + rc * 8, 64)) = v;
    }
  }
}

// ---------------- conversions ----------------

__global__ __launch_bounds__(256) void conv_k(const float* __restrict__ in,
                                              us* __restrict__ out, int n) {
  for (int i = blockIdx.x * 256 + threadIdx.x; i < n; i += gridDim.x * 256)
    out[i] = f2bf(in[i]);
}

__global__ void tconv_k(const float* __restrict__ in, us* __restrict__ out, int R, int C) {
  __shared__ float tile[32][33];
  int c0 = blockIdx.x * 32, r0 = blockIdx.y * 32;
  int tx = threadIdx.x, ty = threadIdx.y;
#pragma unroll
  for (int j = 0; j < 4; ++j)
    tile[ty + 8 * j][tx] = in[(size_t)(r0 + ty + 8 * j) * C + c0 + tx];
  __syncthreads();
#pragma unroll
  for (int j = 0; j < 4; ++j)
    out[(size_t)(c0 + ty + 8 * j) * R + r0 + tx] = f2bf(tile[tx][ty + 8 * j]);
}

// ---------------- elementwise / reductions ----------------

__global__ __launch_bounds__(256) void polynorm2_k(const float* __restrict__ lin,
                                                   us* __restrict__ outp) {
  __shared__ float red[256];
  int n = blockIdx.x, t = threadIdx.x;
  int rowp = cm_map(n);
  float s = 0.f;
  for (int f = t; f < 512; f += 256) { float v = lin[(size_t)n * 512 + f]; s += v * v; }
  float tot = block_reduce_sum(s, red);
  float sc = 1.0f / fmaxf(sqrtf(tot), 1e-12f);
  const float is2 = 0.70710678118654752f;
  for (int f = t; f < 512; f += 256) {
    float v = lin[(size_t)n * 512 + f] * sc;
    outp[(size_t)rowp * 1024 + f] = f2bf(v * is2);
    outp[(size_t)rowp * 1024 + 512 + f] = f2bf(v * v * is2);
  }
}

__global__ __launch_bounds__(256) void gates_k(const float* __restrict__ x,
    const float* __restrict__ wlr, const float* __restrict__ blr,
    const float* __restrict__ wmom, const float* __restrict__ bmom,
    const float* __restrict__ wdec, const float* __restrict__ bdec,
    const float* __restrict__ wgate, const float* __restrict__ bgate,
    float* __restrict__ lrv, float* __restrict__ momv,
    float* __restrict__ decv, float* __restrict__ og) {
  __shared__ float red[256];
  int n = blockIdx.x, t = threadIdx.x;
  float s0 = 0.f, s1 = 0.f, s2 = 0.f, s3 = 0.f;
  for (int d = t; d < 2048; d += 256) {
    float xv = x[(size_t)n * 2048 + d];
    s0 += xv * wlr[d]; s1 += xv * wmom[d]; s2 += xv * wdec[d]; s3 += xv * wgate[d];
  }
  float r0 = block_reduce_sum(s0, red);
  float r1 = block_reduce_sum(s1, red);
  float r2 = block_reduce_sum(s2, red);
  float r3 = block_reduce_sum(s3, red);
  if (t == 0) {
    lrv[n] = sigmoid_f(r0 + blr[0]);
    momv[n] = sigmoid_f(r1 + bmom[0]);
    decv[n] = sigmoid_f(r2 + bdec[0]);
    og[n] = sigmoid_f(r3 + bgate[0]);
  }
}

__global__ void chunk_means_k(const float* __restrict__ lrv, const float* __restrict__ momv,
                              const float* __restrict__ decv, float* __restrict__ cp) {
  int c = blockIdx.x, t = threadIdx.x;  // 64 threads
  int n = ((t >> 5) << 10) + c * 32 + (t & 31);
  float a = lrv[n], b = momv[n], d = decv[n];
  for (int off = 32; off > 0; off >>= 1) {
    a += __shfl_down(a, off);
    b += __shfl_down(b, off);
    d += __shfl_down(d, off);
  }
  if (t == 0) {
    cp[c * 3 + 0] = a * (1.f / 64.f);
    cp[c * 3 + 1] = b * (1.f / 64.f);
    cp[c * 3 + 2] = d * (1.f / 64.f);
  }
}

__global__ __launch_bounds__(256) void sampnorm2_k(const us* __restrict__ kp_b,
                                                   const float* __restrict__ dh,
                                                   const us* __restrict__ hab,
                                                   const us* __restrict__ pr,
                                                   float* __restrict__ w0inv,
                                                   float* __restrict__ w1inv, int c) {
  __shared__ float red[256];
  int i = blockIdx.x, t = threadIdx.x;
  int row = c * 64 + i;
  float sk = 0.f, sr = 0.f, sdh = 0.f, sa = 0.f;
  for (int p = t; p < 1024; p += 256) {
    float v = bf2f(kp_b[(size_t)row * 1024 + p]); sk += v * v;
    v = bf2f(pr[(size_t)(64 + i) * 1024 + p]); sr += v * v;
  }
  for (int h = t; h < 2048; h += 256) {
    float v = dh[(size_t)i * 2048 + h]; sdh += v * v;
    v = bf2f(hab[(size_t)(64 + i) * 2048 + h]); sa += v * v;
  }
  float tk = block_reduce_sum(sk, red);
  float tdh = block_reduce_sum(sdh, red);
  float ta = block_reduce_sum(sa, red);
  float tr = block_reduce_sum(sr, red);
  if (t == 0) {
    float n0 = fmaxf(sqrtf(tk) * sqrtf(tdh), 1e-8f);
    w0inv[i] = 1.0f / (64.0f * fmaxf(n0 * 0.1f, 1.0f));
    float n1 = fmaxf(sqrtf(ta) * sqrtf(tr), 1e-8f);
    w1inv[i] = 1.0f / (64.0f * fmaxf(n1 * 0.1f, 1.0f));
  }
}

__global__ __launch_bounds__(256) void frob2_k(const float* __restrict__ s0,
                                               const float* __restrict__ s1, int n,
                                               float* __restrict__ parts) {
  __shared__ float red[256];
  const float* s = blockIdx.z ? s1 : s0;
  float acc = 0.f;
  for (int i = blockIdx.x * 256 + threadIdx.x; i < n; i += gridDim.x * 256) {
    float v = s[i]; acc += v * v;
  }
  float r = block_reduce_sum(acc, red);
  if (threadIdx.x == 0) parts[blockIdx.z * 256 + blockIdx.x] = r;
}

__global__ __launch_bounds__(256) void frob_fin2_k(const float* __restrict__ parts,
                                                   float* __restrict__ inv) {
  __shared__ float red[256];
  float r = block_reduce_sum(parts[blockIdx.x * 256 + threadIdx.x], red);
  if (threadIdx.x == 0) inv[blockIdx.x] = 1.0f / (sqrtf(r) + 1e-7f);
}

__global__ void wupd0_k(float* __restrict__ W0, const us* __restrict__ X,
                        us* __restrict__ W0bT, const float* __restrict__ cp, int c) {
  __shared__ float tl[32][33];
  float lr = cp[c * 3 + 0], om = 1.0f - cp[c * 3 + 2];
  int c0 = blockIdx.x * 32, r0 = blockIdx.y * 32;
  int tx = threadIdx.x, ty = threadIdx.y;
#pragma unroll
  for (int j = 0; j < 4; ++j) {
    int r = r0 + ty + 8 * j, h = c0 + tx;
    size_t idx = (size_t)r * 2048 + h;
    float v = om * W0[idx] + lr * bf2f(X[idx]);
    W0[idx] = v;
    tl[ty + 8 * j][tx] = v;
  }
  __syncthreads();
#pragma unroll
  for (int j = 0; j < 4; ++j)
    W0bT[(size_t)(c0 + ty + 8 * j) * 1024 + r0 + tx] = f2bf(tl[tx][ty + 8 * j]);
}

__global__ void wupd1_k(float* __restrict__ W1, const us* __restrict__ X2,
                        us* __restrict__ W1b, us* __restrict__ W1bT,
                        const float* __restrict__ cp, int c) {
  __shared__ float tX[32][33];
  __shared__ float t2[32][33];
  float lr = cp[c * 3 + 0], om = 1.0f - cp[c * 3 + 2];
  int h0 = blockIdx.x * 32, p0 = blockIdx.y * 32;
  int tx = threadIdx.x, ty = threadIdx.y;
#pragma unroll
  for (int j = 0; j < 4; ++j)
    tX[ty + 8 * j][tx] = bf2f(X2[(size_t)(p0 + ty + 8 * j) * 2048 + h0 + tx]);
  __syncthreads();
#pragma unroll
  for (int j = 0; j < 4; ++j) {
    int h = h0 + ty + 8 * j, p = p0 + tx;
    size_t idx = (size_t)h * 1024 + p;
    float v = om * W1[idx] + lr * tX[tx][ty + 8 * j];
    W1[idx] = v;
    W1b[idx] = f2bf(v);
    t2[tx][ty + 8 * j] = v;
  }
  __syncthreads();
#pragma unroll
  for (int j = 0; j < 4; ++j)
    W1bT[(size_t)(p0 + ty + 8 * j) * 2048 + h0 + tx] = f2bf(t2[ty + 8 * j][tx]);
}

// ---------------- host ----------------

extern "C" void kernel_launch(void* const* d_in, const int* in_sizes, int n_in,
                              void* d_out, int out_size, void* d_ws, size_t ws_size,
                              hipStream_t stream) {
  const float* x = (const float*)d_in[0];
  const float* Wk = (const float*)d_in[1];
  const float* Wv = (const float*)d_in[2];
  const float* Wq = (const float*)d_in[3];
  const float* Wout = (const float*)d_in[4];
  const float* w_lr = (const float*)d_in[5];
  const float* b_lr = (const float*)d_in[6];
  const float* w_mom = (const float*)d_in[7];
  const float* b_mom = (const float*)d_in[8];
  const float* w_dec = (const float*)d_in[9];
  const float* b_dec = (const float*)d_in[10];
  const float* w_gate = (const float*)d_in[11];
  const float* b_gate = (const float*)d_in[12];
  const float* Wmem0 = (const float*)d_in[13];
  const float* Wmem1 = (const float*)d_in[14];
  const float* Wmemout = (const float*)d_in[15];
  const float* Wvexp = (const float*)d_in[16];
  float* out = (float*)d_out;
  (void)n_in; (void)in_sizes; (void)out_size;

  const long F = 1048576;
  const long BIG = 2097152;
  const long SB2 = 2097152, SB1 = 1048576;
  float* ws = (float*)d_ws;
  if (ws_size < (size_t)25043464 * sizeof(float)) return;

  us* kp_b   = (us*)ws;               // [0,1F)
  us* qp_b   = (us*)(ws + F);         // [1,2)
  float* vexp = ws + 2 * F;           // [2,4)
  float* W0  = ws + 4 * F;            // [4,6)
  float* W1  = ws + 6 * F;            // [6,8)
  float* S0  = ws + 8 * F;            // [8,10)
  float* S1  = ws + 10 * F;           // [10,12)
  us* XPong  = (us*)(ws + 12 * F);    // [12,14) pong packed X | Xfin rm | xb
  us* XTPong = (us*)(ws + 14 * F);    // [14,16) pong packed XT | Wkb/Wqb/Wvb
  us* XPing  = (us*)(ws + 16 * F);    // [16,18) ping packed X | vlin/WvexpT
  us* AP     = (us*)(ws + 18 * F);    // [18,19) packed A | Woutb (final)
  float* SCR = ws + 19 * F;           // [19,20) chunk scratch
  us* XTPing = (us*)(ws + 20 * F);    // [20,22) ping packed XT (= W0bT/W1bT)
  us* BP     = (us*)(ws + 22 * F);    // [22,23) packed B (= W1b)
  us* W0bT   = (us*)(ws + 20 * F);    // chunk-path alias (regenerated by wupd0)
  us* W1bT   = (us*)(ws + 21 * F);
  us* W1b    = (us*)(ws + 22 * F);
  us* WmoT   = (us*)(ws + 23 * F);    // [23,23.25)
  us* retrv  = (us*)(ws + 23 * F + 262144);
  float* smal = ws + 23 * F + 262144 + 524288;
  float* og   = smal;
  float* lrv  = og + 2048;
  float* momv = lrv + 2048;
  float* decv = momv + 2048;
  float* cpb  = decv + 2048;
  float* w0inv = cpb + 128;
  float* w1inv = w0inv + 64;
  float* parts = w1inv + 64;
  float* inv01 = parts + 512;

  us* xb   = XPong;                    // prologue aliases
  us* Wkb  = XTPong;
  us* Wqb  = XTPong + 1048576;
  us* Wvb  = XTPong + 2097152;
  us* vlin = XPing;
  us* WvexpT = XPing + 1048576;
  us* Woutb = AP;
  float* lin = SCR;
  us* hab   = (us*)SCR;
  float* gp = SCR + 131072;
  us* pr    = (us*)(SCR + 262144);
  float* dh = SCR + 327680;
  us* dhT   = (us*)(SCR + 458752);
  us* rbwT  = (us*)(SCR + 524288);
  us* Xfin  = XPong;                   // final NS output rm [2][1024][2048]

  const float NSa = 3.4445f, NSb = -4.7750f, NSc = 2.0315f;

  hipMemcpyAsync(W0, Wmem0, (size_t)BIG * 4, hipMemcpyDeviceToDevice, stream);
  hipMemcpyAsync(W1, Wmem1, (size_t)BIG * 4, hipMemcpyDeviceToDevice, stream);
  hipMemsetAsync(S0, 0, (size_t)BIG * 4, stream);
  hipMemsetAsync(S1, 0, (size_t)BIG * 4, stream);
  hipLaunchKernelGGL(tconv_k, dim3(64, 32), dim3(32, 8), 0, stream, Wmem0, W0bT, 1024, 2048);
  hipLaunchKernelGGL(conv_k, dim3(1024), dim3(256), 0, stream, Wmem1, W1b, (int)BIG);
  hipLaunchKernelGGL(tconv_k, dim3(32, 64), dim3(32, 8), 0, stream, Wmem1, W1bT, 2048, 1024);
  hipLaunchKernelGGL(tconv_k, dim3(16, 32), dim3(32, 8), 0, stream, Wmemout, WmoT, 1024, 512);
  hipLaunchKernelGGL(tconv_k, dim3(32, 16), dim3(32, 8), 0, stream, Wvexp, WvexpT, 512, 1024);
  hipLaunchKernelGGL(conv_k, dim3(2048), dim3(256), 0, stream, x, xb, 2048 * 2048);
  hipLaunchKernelGGL(conv_k, dim3(512), dim3(256), 0, stream, Wk, Wkb, 512 * 2048);
  hipLaunchKernelGGL(conv_k, dim3(512), dim3(256), 0, stream, Wq, Wqb, 512 * 2048);
  hipLaunchKernelGGL(conv_k, dim3(512), dim3(256), 0, stream, Wv, Wvb, 512 * 2048);

  mg<7>(stream, xb, nullptr, Wkb, lin, nullptr, nullptr, nullptr, nullptr, nullptr, 0,
        2048, 512, 2048, 2048, 2048, 512, 0);
  hipLaunchKernelGGL(polynorm2_k, dim3(2048), dim3(256), 0, stream, lin, kp_b);
  mg<7>(stream, xb, nullptr, Wqb, lin, nullptr, nullptr, nullptr, nullptr, nullptr, 0,
        2048, 512, 2048, 2048, 2048, 512, 0);
  hipLaunchKernelGGL(polynorm2_k, dim3(2048), dim3(256), 0, stream, lin, qp_b);
  mg<5>(stream, xb, nullptr, Wvb, vlin, nullptr, nullptr, nullptr, nullptr, nullptr, 0,
        2048, 512, 2048, 2048, 2048, 512, 0);
  mg<17>(stream, vlin, nullptr, WvexpT, vexp, nullptr, nullptr, nullptr, nullptr, nullptr, 0,
         2048, 1024, 512, 512, 512, 1024, 0);

  hipLaunchKernelGGL(gates_k, dim3(2048), dim3(256), 0, stream, x,
                     w_lr, b_lr, w_mom, b_mom, w_dec, b_dec, w_gate, b_gate,
                     lrv, momv, decv, og);
  hipLaunchKernelGGL(chunk_means_k, dim3(32), dim3(64), 0, stream, lrv, momv, decv, cpb);

  for (int c = 0; c < 32; ++c) {
    const us* kp_c = kp_b + (size_t)c * 64 * 1024;
    const us* qp_c = qp_b + (size_t)c * 64 * 1024;
    const float* vexp_c = vexp + (size_t)c * 64 * 1024;
    mg<8, 0, 1>(stream, qp_c, kp_c, W0bT, hab, gp, nullptr, nullptr, nullptr, nullptr, 0,
                128, 2048, 1024, 1024, 1024, 2048, 0);
    mg<9>(stream, hab, nullptr, W1bT, pr, nullptr, vexp_c, nullptr, nullptr, nullptr, 0,
          128, 1024, 2048, 2048, 2048, 1024, 1024);
    mg<5>(stream, pr, nullptr, WmoT, retrv + (size_t)c * 64 * 512, nullptr, nullptr,
          nullptr, nullptr, nullptr, 0, 64, 512, 1024, 1024, 1024, 512, 0);
    mg<13>(stream, pr + 64 * 1024, nullptr, W1b, dh, nullptr, gp, nullptr, nullptr, nullptr, 0,
           64, 2048, 1024, 1024, 1024, 2048, 2048);
    hipLaunchKernelGGL(sampnorm2_k, dim3(64), dim3(256), 0, stream,
                       kp_b, dh, hab, pr, w0inv, w1inv, c);
    hipLaunchKernelGGL(wt2_k, dim3(192), dim3(32, 8), 0, stream,
                       dh, w0inv, dhT, pr + 64 * 1024, w1inv, rbwT);
    hipLaunchKernelGGL(mg2_k, dim3(1024), dim3(64), 0, stream,
                       kp_c, dhT, S0, hab + 64 * 2048, rbwT, S1, cpb, c);

    // ---- batched NS5: batch0 = S0 (1024x2048), batch1 = S1^T ----
    hipLaunchKernelGGL(frob2_k, dim3(256, 1, 2), dim3(256), 0, stream, S0, S1, (int)BIG, parts);
    hipLaunchKernelGGL(frob_fin2_k, dim3(2), dim3(256), 0, stream, parts, inv01);
    hipLaunchKernelGGL(scalepk2_k, dim3(64, 32, 2), dim3(32, 8), 0, stream,
                       S0, S1, inv01, XPing, XTPing);

    us* xpA[2] = {XPing, XPong};
    us* xtA[2] = {XTPing, XTPong};
    int cur = 0;
    for (int it = 0; it < 5; ++it) {
      const us* XPc = xpA[cur];
      const us* XTPc = xtA[cur];
      int nxt = cur ^ 1;
      // AP = pack(Xc @ Xc^T)  (triangular: 36/64 tiles + mirror writes)
      mgp<20, 1, 8, 8>(stream, XPc, XPc, AP, nullptr, nullptr, 2048, 1024,
                       0.f, 0.f, SB2, SB2, SB1, 0);
      // BP = pack(NSc*(A@A) + NSb*A)  (triangular, K=1024)
      mgp<21, 1, 8, 8>(stream, AP, AP, BP, nullptr, AP, 1024, 1024,
                       NSc, NSb, SB1, SB1, SB1, SB1);
      if (it < 4) {
        // XPn/XTn = pack(B@Xc + NSa*Xc)
        mgp<23, 0, 8, 16>(stream, BP, XTPc, xpA[nxt], xtA[nxt], XPc, 1024, 2048,
                          NSa, 0.f, SB1, SB2, SB2, SB2);
        cur = nxt;
      } else {
        // Xfin (row-major) = B@Xc + NSa*Xc
        mgp<24, 0, 8, 16>(stream, BP, XTPc, Xfin, nullptr, XPc, 1024, 2048,
                          NSa, 0.f, SB1, SB2, SB2, SB2);
      }
    }
    hipLaunchKernelGGL(wupd0_k, dim3(64, 32), dim3(32, 8), 0, stream, W0, Xfin, W0bT, cpb, c);
    hipLaunchKernelGGL(wupd1_k, dim3(64, 32), dim3(32, 8), 0, stream, W1, Xfin + SB2, W1b, W1bT, cpb, c);
  }

  hipLaunchKernelGGL(conv_k, dim3(1024), dim3(256), 0, stream, Wout, Woutb, 2048 * 512);
  mg<15, 0, 0, 1>(stream, retrv, nullptr, Woutb, out, nullptr, nullptr, x, og, nullptr, 0,
                  2048, 2048, 512, 512, 512, 2048, 0);
}

// Round 17
// 15344.781 us; speedup vs baseline: 1.1098x; 1.1098x over previous
//
#include <hip/hip_runtime.h>

// ---------------------------------------------------------------------------
// DeepMemoryLevel (ATLAS-style). B=2 S=1024 D=2048 M=512 P=1024 H=2048
// CHUNK=32 NC=32, tokens N=2048.
// Round 17: revert R16's triangular square-GEMM grids (72 blocks -> too few;
// latency component dominates the traffic savings). Keep the bit-exact
// launch merges (wt2 = wtrans pair, mg2 = G5+G6, scalepk2). NS GEMMs on
// R15's 4-wave 128x128 packed-fragment LDS-free tiles, full grids.
// ---------------------------------------------------------------------------

typedef unsigned short us;
typedef __attribute__((ext_vector_type(8))) short s16x8;
typedef __attribute__((ext_vector_type(8))) unsigned short u16x8;
typedef __attribute__((ext_vector_type(4))) float f32x4;

#define MKP 72

__device__ __forceinline__ float gelu_f(float x) {
  return 0.5f * x * (1.0f + erff(x * 0.70710678118654752f));
}
__device__ __forceinline__ float gelu_grad_f(float x) {
  float cdf = 0.5f * (1.0f + erff(x * 0.70710678118654752f));
  float pdf = 0.3989422804014327f * expf(-0.5f * x * x);
  return cdf + x * pdf;
}
__device__ __forceinline__ float sigmoid_f(float x) { return 1.0f / (1.0f + expf(-x)); }

__device__ __forceinline__ us f2bf(float f) {
  union { float f; unsigned u; } v; v.f = f;
  unsigned r = (v.u + 0x7FFFu + ((v.u >> 16) & 1u)) >> 16;
  return (us)r;
}
__device__ __forceinline__ float bf2f(us h) {
  union { unsigned u; float f; } v; v.u = ((unsigned)h) << 16;
  return v.f;
}
// token-major index n -> chunk-major row
__device__ __forceinline__ int cm_map(int n) {
  return ((n & 1023) >> 5) * 64 + (n >> 10) * 32 + (n & 31);
}
// packed-fragment offset: matrix R x K (row-major source), element (r,k).
__device__ __forceinline__ size_t pf_off(int r, int k, int KB) {
  return ((size_t)(r >> 4) * KB + (k >> 5)) * 512 + ((k >> 3) & 3) * 128 + (r & 15) * 8 + (k & 7);
}

__device__ __forceinline__ float block_reduce_sum(float v, float* red) {
  int t = threadIdx.x;
  red[t] = v; __syncthreads();
  for (int s = blockDim.x >> 1; s > 0; s >>= 1) {
    if (t < s) red[t] += red[t + s];
    __syncthreads();
  }
  float r = red[0];
  __syncthreads();
  return r;
}

// ---------------- packed-fragment GEMM core (R12-proven) ----------------
__device__ __forceinline__ void gemm_pk(const us* __restrict__ A,
                                        const us* __restrict__ B, int KB,
                                        int lane, int m0, int n0,
                                        f32x4 (&acc)[4][4]) {
  const us* am[4];
  const us* bm[4];
#pragma unroll
  for (int q = 0; q < 4; ++q) {
    am[q] = A + (size_t)((m0 >> 4) + q) * KB * 512 + lane * 8;
    bm[q] = B + (size_t)((n0 >> 4) + q) * KB * 512 + lane * 8;
  }
#pragma unroll
  for (int i = 0; i < 4; ++i)
#pragma unroll
    for (int j = 0; j < 4; ++j) acc[i][j] = (f32x4){0.f, 0.f, 0.f, 0.f};
  u16x8 a0[4], b0[4], a1[4], b1[4];
#pragma unroll
  for (int q = 0; q < 4; ++q) {
    a0[q] = *(const u16x8*)(am[q]);
    b0[q] = *(const u16x8*)(bm[q]);
    a1[q] = *(const u16x8*)(am[q] + 512);
    b1[q] = *(const u16x8*)(bm[q] + 512);
  }
  for (int kb = 0; kb < KB; kb += 2) {
#pragma unroll
    for (int mi = 0; mi < 4; ++mi)
#pragma unroll
      for (int ni = 0; ni < 4; ++ni)
        acc[mi][ni] = __builtin_amdgcn_mfma_f32_16x16x32_bf16(
            (s16x8)a0[mi], (s16x8)b0[ni], acc[mi][ni], 0, 0, 0);
    if (kb + 2 < KB) {
#pragma unroll
      for (int q = 0; q < 4; ++q) {
        a0[q] = *(const u16x8*)(am[q] + (size_t)(kb + 2) * 512);
        b0[q] = *(const u16x8*)(bm[q] + (size_t)(kb + 2) * 512);
      }
    }
#pragma unroll
    for (int mi = 0; mi < 4; ++mi)
#pragma unroll
      for (int ni = 0; ni < 4; ++ni)
        acc[mi][ni] = __builtin_amdgcn_mfma_f32_16x16x32_bf16(
            (s16x8)a1[mi], (s16x8)b1[ni], acc[mi][ni], 0, 0, 0);
    if (kb + 3 < KB) {
#pragma unroll
      for (int q = 0; q < 4; ++q) {
        a1[q] = *(const u16x8*)(am[q] + (size_t)(kb + 3) * 512);
        b1[q] = *(const u16x8*)(bm[q] + (size_t)(kb + 3) * 512);
      }
    }
  }
}

// ---------------- 4-wave 128x128 packed MFMA GEMM (barrier-free) ----------
// Each wave computes an independent 64x64 quadrant (wm,wn). Co-scheduled
// waves share A/B panels pairwise (L1/L2 dedupe).
// EPI 20: C packed (KC = N>>5).
// EPI 21: C packed = c1*acc + c2*E_packed (same layout).
// EPI 23: X-update it<4: o = acc + c1*E(XPc packed KB=64);
//         C=XPn packed (KB=64), C2=XTPn packed ([2048][1024], KB=32).
// EPI 24: X-update it=4: o = acc + c1*E(packed KB=64); C row-major ldc=2048.
template<int EPI, int TM, int TN>
__global__ __launch_bounds__(256)
void mgp_k(const us* __restrict__ Aq, const us* __restrict__ Bq,
           us* __restrict__ Cq, us* __restrict__ C2q, const us* __restrict__ Eq,
           int K, int N, float c1, float c2,
           long sA, long sB, long sC, long sE) {
  __shared__ __align__(16) us ct[4 * 64 * 72];
  const int tid = threadIdx.x;
  const int wave = tid >> 6, lane = tid & 63;
  const int l15 = lane & 15, l4 = lane >> 4;
  const int wm = (wave >> 1) * 64, wn = (wave & 1) * 64;
  const int TPB = TM * TN;
  const int t = blockIdx.x;
  const int bz = t / TPB;
  const int ti = t - bz * TPB;
  const int m0 = (ti / TN) * 128 + wm;
  const int n0 = (ti % TN) * 128 + wn;

  const us* A = Aq + (size_t)bz * sA;
  const us* B = Bq + (size_t)bz * sB;
  us* C = Cq + (size_t)bz * sC;
  us* C2 = C2q + (size_t)bz * sC;
  const us* E = Eq + (size_t)bz * sE;
  const int KB = K >> 5;

  f32x4 acc[4][4];
  gemm_pk(A, B, KB, lane, m0, n0, acc);

  us* cw = ct + wave * 64 * 72;
  // stage quadrant into per-wave LDS slice (1 wave: in-order DS, no barrier)
#pragma unroll
  for (int mi = 0; mi < 4; ++mi)
#pragma unroll
    for (int i = 0; i < 4; ++i)
#pragma unroll
      for (int ni = 0; ni < 4; ++ni)
        cw[(mi * 16 + l4 * 4 + i) * 72 + ni * 16 + l15] = f2bf(acc[mi][ni][i]);

  if constexpr (EPI == 20 || EPI == 21) {
    const int KC = N >> 5;
#pragma unroll
    for (int q = 0; q < 8; ++q) {
      u16x8 v = *(const u16x8*)&cw[lane * 72 + q * 8];
      size_t off = pf_off(m0 + lane, n0 + q * 8, KC);
      if constexpr (EPI == 21) {
        u16x8 e = *(const u16x8*)(E + off);
        u16x8 o;
#pragma unroll
        for (int w = 0; w < 8; ++w) o[w] = f2bf(c1 * bf2f(v[w]) + c2 * bf2f(e[w]));
        *(u16x8*)(C + off) = o;
      } else {
        *(u16x8*)(C + off) = v;
      }
    }
  } else if constexpr (EPI == 23) {
    // combine with c1*E (E = Xc packed, KB=64), write XPn; update cw in place
#pragma unroll
    for (int q = 0; q < 8; ++q) {
      size_t off = pf_off(m0 + lane, n0 + q * 8, 64);
      u16x8 v = *(const u16x8*)&cw[lane * 72 + q * 8];
      u16x8 e = *(const u16x8*)(E + off);
      u16x8 o;
#pragma unroll
      for (int w = 0; w < 8; ++w) o[w] = f2bf(bf2f(v[w]) + c1 * bf2f(e[w]));
      *(u16x8*)&cw[lane * 72 + q * 8] = o;
      *(u16x8*)(C + off) = o;
    }
    // packed transpose out: XT[2048][1024], KB=32 (same-wave DS ordering safe)
#pragma unroll
    for (int q = 0; q < 8; ++q) {
      u16x8 o;
#pragma unroll
      for (int w = 0; w < 8; ++w) o[w] = cw[(q * 8 + w) * 72 + lane];
      size_t offT = pf_off(n0 + lane, m0 + q * 8, 32);
      *(u16x8*)(C2 + offT) = o;
    }
  } else {  // EPI 24: row-major out [1024][2048], combine with c1*E packed
#pragma unroll
    for (int q = 0; q < 8; ++q) {
      size_t off = pf_off(m0 + lane, n0 + q * 8, 64);
      u16x8 v = *(const u16x8*)&cw[lane * 72 + q * 8];
      u16x8 e = *(const u16x8*)(E + off);
      u16x8 o;
#pragma unroll
      for (int w = 0; w < 8; ++w) o[w] = f2bf(bf2f(v[w]) + c1 * bf2f(e[w]));
      *(u16x8*)(C + (size_t)(m0 + lane) * 2048 + n0 + q * 8) = o;
    }
  }
}

template<int EPI, int TM, int TN>
static void mgp(hipStream_t st, const us* A, const us* B, us* C, us* C2,
                const us* E, int K, int N, float c1, float c2,
                long sA, long sB, long sC, long sE) {
  dim3 g(TM * TN * 2), b(256);
  hipLaunchKernelGGL((mgp_k<EPI, TM, TN>), g, b, 0, st, A, B, C, C2, E,
                     K, N, c1, c2, sA, sB, sC, sE);
}

// ---------------- epilogue for LDS GEMM (chunk path) ----------------
template<int EPI>
__device__ __forceinline__ void epilogue(f32x4 (&acc)[4][4], int m0, int n0,
    int l15, int l4, void* Cq, void* C2, const void* Eq,
    const float* FX, const float* OG, const float* cp, int cidx,
    int ldc, int lde, float c1, float c2) {
#pragma unroll
  for (int mi = 0; mi < 4; ++mi) {
#pragma unroll
    for (int i = 0; i < 4; ++i) {
      int grow = m0 + mi * 16 + l4 * 4 + i;
#pragma unroll
      for (int ni = 0; ni < 4; ++ni) {
        int col = n0 + ni * 16 + l15;
        float v = acc[mi][ni][i];
        if constexpr (EPI == 5) {
          ((us*)Cq)[(size_t)grow * ldc + col] = f2bf(v);
        } else if constexpr (EPI == 7) {
          ((float*)Cq)[(size_t)grow * ldc + col] = v;
        } else if constexpr (EPI == 8) {
          ((us*)Cq)[(size_t)grow * ldc + col] = f2bf(gelu_f(v));
          if (m0 >= 64)
            ((float*)C2)[(size_t)(grow - 64) * ldc + col] = gelu_grad_f(v);
        } else if constexpr (EPI == 9) {
          if (m0 < 64)
            ((us*)Cq)[(size_t)grow * ldc + col] = f2bf(v);
          else
            ((us*)Cq)[(size_t)grow * ldc + col] =
                f2bf(2.0f * (v - ((const float*)Eq)[(size_t)(grow - 64) * lde + col]));
        } else if constexpr (EPI == 13) {
          ((float*)Cq)[(size_t)grow * ldc + col] =
              v * ((const float*)Eq)[(size_t)grow * lde + col];
        } else if constexpr (EPI == 14) {
          float* C = (float*)Cq;
          float old = C[(size_t)grow * ldc + col];
          C[(size_t)grow * ldc + col] = cp[cidx * 3 + 1] * old - cp[cidx * 3 + 0] * v;
        } else if constexpr (EPI == 15) {
          ((float*)Cq)[(size_t)grow * ldc + col] =
              FX[(size_t)grow * ldc + col] + v * OG[grow];
        } else if constexpr (EPI == 17) {
          int crow = cm_map(grow);
          ((float*)Cq)[(size_t)crow * ldc + col] = v;
        }
      }
    }
  }
}

// ---------------- 1-wave 64x64 LDS GEMM body (chunk path) ----------------
template<int EPI, int TA, int DUAL, int AG>
__device__ __forceinline__ void mg_body(const us* __restrict__ A0,
    const us* __restrict__ A2, const us* __restrict__ B,
    void* __restrict__ Cq, void* __restrict__ C2, const void* __restrict__ Eq,
    const float* __restrict__ FX, const float* __restrict__ OG,
    const float* __restrict__ cp, int cidx, int m0, int n0,
    int K, int lda, int ldb, int ldc, int lde, float c1, float c2,
    us* As, us* Bs, int t) {
  const us* A = A0;
  if constexpr (DUAL) { if (m0 >= 64) A = A2; }
  const int mA0 = DUAL ? (m0 & 63) : m0;
  const int l15 = t & 15, l4 = t >> 4;

  f32x4 acc[4][4];
#pragma unroll
  for (int i = 0; i < 4; ++i)
#pragma unroll
    for (int j = 0; j < 4; ++j) acc[i][j] = (f32x4){0.f, 0.f, 0.f, 0.f};

  const int srw = t >> 3;
  const int sck = (t & 7) * 8;

  u16x8 ra[8], rb[8];
  auto LDA = [&](int k0) {
#pragma unroll
    for (int p = 0; p < 8; ++p) {
      if constexpr (TA == 0) {
        int row = srw + p * 8;
        int srow;
        if constexpr (AG) srow = cm_map(m0 + row); else srow = mA0 + row;
        ra[p] = *(const u16x8*)(A + (size_t)srow * lda + k0 + sck);
      } else {
        ra[p] = *(const u16x8*)(A + (size_t)(k0 + srw + p * 8) * lda + mA0 + sck);
      }
    }
  };
  auto LDB = [&](int k0) {
#pragma unroll
    for (int p = 0; p < 8; ++p)
      rb[p] = *(const u16x8*)(B + (size_t)(n0 + srw + p * 8) * ldb + k0 + sck);
  };

  LDA(0); LDB(0);
  for (int k0 = 0; k0 < K; k0 += 64) {
    if constexpr (TA == 0) {
#pragma unroll
      for (int p = 0; p < 8; ++p)
        *(u16x8*)&As[(srw + p * 8) * MKP + sck] = ra[p];
    } else {
#pragma unroll
      for (int p = 0; p < 8; ++p) {
        int kk = srw + p * 8;
#pragma unroll
        for (int j = 0; j < 8; ++j) As[(sck + j) * MKP + kk] = ra[p][j];
      }
    }
#pragma unroll
    for (int p = 0; p < 8; ++p)
      *(u16x8*)&Bs[(srw + p * 8) * MKP + sck] = rb[p];
    if (k0 + 64 < K) { LDA(k0 + 64); LDB(k0 + 64); }
#pragma unroll
    for (int ks = 0; ks < 2; ++ks) {
      s16x8 af[4], bf[4];
#pragma unroll
      for (int mi = 0; mi < 4; ++mi)
        af[mi] = *(const s16x8*)&As[(mi * 16 + l15) * MKP + ks * 32 + l4 * 8];
#pragma unroll
      for (int ni = 0; ni < 4; ++ni)
        bf[ni] = *(const s16x8*)&Bs[(ni * 16 + l15) * MKP + ks * 32 + l4 * 8];
#pragma unroll
      for (int mi = 0; mi < 4; ++mi)
#pragma unroll
        for (int ni = 0; ni < 4; ++ni)
          acc[mi][ni] = __builtin_amdgcn_mfma_f32_16x16x32_bf16(af[mi], bf[ni], acc[mi][ni], 0, 0, 0);
    }
  }

  epilogue<EPI>(acc, m0, n0, l15, l4, Cq, C2, Eq, FX, OG, cp, cidx,
                ldc, lde, c1, c2);
}

template<int EPI, int TA, int DUAL, int AG>
__global__ __launch_bounds__(64)
void mg_k(const us* __restrict__ Aq, const us* __restrict__ A2,
          const us* __restrict__ Bq, void* __restrict__ Cq,
          void* __restrict__ C2, const void* __restrict__ Eq,
          const float* __restrict__ FX, const float* __restrict__ OG,
          const float* __restrict__ cp, int cidx,
          int M, int N, int K, int lda, int ldb, int ldc, int lde,
          float c1, float c2) {
  __shared__ __align__(16) us As[64 * MKP];
  __shared__ __align__(16) us Bs[64 * MKP];
  mg_body<EPI, TA, DUAL, AG>(Aq, A2, Bq, Cq, C2, Eq, FX, OG, cp, cidx,
                             blockIdx.y * 64, blockIdx.x * 64, K, lda, ldb,
                             ldc, lde, c1, c2, As, Bs, threadIdx.x);
}

template<int EPI, int TA = 0, int DUAL = 0, int AG = 0>
static void mg(hipStream_t st, const us* A, const us* A2, const us* B,
               void* C, void* C2, const void* E,
               const float* FX, const float* OG, const float* cp, int cidx,
               int M, int N, int K, int lda, int ldb, int ldc, int lde,
               float c1 = 0.f, float c2 = 0.f) {
  dim3 g(N / 64, M / 64, 1), b(64);
  hipLaunchKernelGGL((mg_k<EPI, TA, DUAL, AG>), g, b, 0, st, A, A2, B, C, C2, E,
                     FX, OG, cp, cidx, M, N, K, lda, ldb, ldc, lde, c1, c2);
}

// ---------------- merged G5+G6 (EPI 14, TA=1): 1024 blocks 1D ----------------
__global__ __launch_bounds__(64)
void mg2_k(const us* __restrict__ kp_c, const us* __restrict__ dhT,
           float* __restrict__ S0, const us* __restrict__ habk,
           const us* __restrict__ rbwT, float* __restrict__ S1,
           const float* __restrict__ cp, int c) {
  __shared__ __align__(16) us As[64 * MKP];
  __shared__ __align__(16) us Bs[64 * MKP];
  int bid = blockIdx.x;
  if (bid < 512) {
    int m0 = (bid >> 5) * 64, n0 = (bid & 31) * 64;   // M=1024, N=2048
    mg_body<14, 1, 0, 0>(kp_c, nullptr, dhT, S0, nullptr, nullptr,
                         nullptr, nullptr, cp, c, m0, n0,
                         64, 1024, 64, 2048, 0, 0.f, 0.f, As, Bs, threadIdx.x);
  } else {
    int b2 = bid - 512;
    int m0 = (b2 >> 4) * 64, n0 = (b2 & 15) * 64;     // M=2048, N=1024
    mg_body<14, 1, 0, 0>(habk, nullptr, rbwT, S1, nullptr, nullptr,
                         nullptr, nullptr, cp, c, m0, n0,
                         64, 2048, 64, 1024, 0, 0.f, 0.f, As, Bs, threadIdx.x);
  }
}

// ---------------- merged wtrans pair: 192 blocks 1D, block (32,8) -----------
__global__ void wt2_k(const float* __restrict__ dh, const float* __restrict__ w0inv,
                      us* __restrict__ dhT, const us* __restrict__ prg,
                      const float* __restrict__ w1inv, us* __restrict__ rbwT) {
  __shared__ float tile[32][33];
  int bid = blockIdx.x;
  int tx = threadIdx.x, ty = threadIdx.y;
  int c0, r0, ldin;
  const float* wv;
  us* outp;
  bool f32in;
  const void* in;
  if (bid < 128) {
    in = dh; wv = w0inv; outp = dhT; ldin = 2048; f32in = true;
    c0 = (bid & 63) * 32; r0 = (bid >> 6) * 32;
  } else {
    int b2 = bid - 128;
    in = prg; wv = w1inv; outp = rbwT; ldin = 1024; f32in = false;
    c0 = (b2 & 31) * 32; r0 = (b2 >> 5) * 32;
  }
#pragma unroll
  for (int j = 0; j < 4; ++j) {
    int r = r0 + ty + 8 * j, cc = c0 + tx;
    float v = f32in ? ((const float*)in)[(size_t)r * ldin + cc]
                    : bf2f(((const us*)in)[(size_t)r * ldin + cc]);
    tile[ty + 8 * j][tx] = v * wv[r];
  }
  __syncthreads();
#pragma unroll
  for (int j = 0; j < 4; ++j)
    outp[(size_t)(c0 + ty + 8 * j) * 64 + r0 + tx] = f2bf(tile[tx][ty + 8 * j]);
}

// ---------------- scale + pack (merged, z=2): S -> XP + XTP packed -----------
__global__ void scalepk2_k(const float* __restrict__ S0, const float* __restrict__ S1,
                           const float* __restrict__ inv01,
                           us* __restrict__ XP, us* __restrict__ XTP) {
  __shared__ float tile[32][33];
  const long SB2c = 2097152;
  int z = blockIdx.z;
  float s = inv01[z];
  int tx = threadIdx.x, ty = threadIdx.y;  // 32 x 8
  int r0, c0;
  const float* S;
  if (z == 0) { S = S0; c0 = blockIdx.x * 32; r0 = blockIdx.y * 32; }
  else        { S = S1; r0 = blockIdx.x * 32; c0 = blockIdx.y * 32; }
  int C = (z == 0) ? 2048 : 1024;
#pragma unroll
  for (int j = 0; j < 4; ++j)
    tile[ty + 8 * j][tx] = S[(size_t)(r0 + ty + 8 * j) * C + c0 + tx] * s;
  __syncthreads();
  us* xp = XP + (size_t)z * SB2c;
  us* xt = XTP + (size_t)z * SB2c;
  int t = ty * 32 + tx;
  if (t < 128) {
    int rh = t >> 2, cc = t & 3;
    u16x8 v;
#pragma unroll
    for (int e = 0; e < 8; ++e) v[e] = f2bf(tile[rh][cc * 8 + e]);
    if (z == 0) {
      *(u16x8*)(xp + pf_off(r0 + rh, c0 + cc * 8, 64)) = v;
    } else {
      *(u16x8*)(xt + pf_off(r0 + rh, c0 + cc * 8, 32)) = v;
    }
  } else {
    int ch = (t - 128) >> 2, rc = (t - 128) & 3;
    u16x8 v;
#pragma unroll
    for (int e = 0; e < 8; ++e) v[e] = f2bf(tile[rc * 8 + e][ch]);
    if (z == 0) {
      *(u16x8*)(xt + pf_off(c0 + ch, r0 + rc * 8, 32)) = v;
    } else {
      *(u16x8*)(xp + pf_off(c0 + ch, r0 + rc * 8, 64)) = v;
    }
  }
}

// ---------------- conversions ----------------

__global__ __launch_bounds__(256) void conv_k(const float* __restrict__ in,
                                              us* __restrict__ out, int n) {
  for (int i = blockIdx.x * 256 + threadIdx.x; i < n; i += gridDim.x * 256)
    out[i] = f2bf(in[i]);
}

__global__ void tconv_k(const float* __restrict__ in, us* __restrict__ out, int R, int C) {
  __shared__ float tile[32][33];
  int c0 = blockIdx.x * 32, r0 = blockIdx.y * 32;
  int tx = threadIdx.x, ty = threadIdx.y;
#pragma unroll
  for (int j = 0; j < 4; ++j)
    tile[ty + 8 * j][tx] = in[(size_t)(r0 + ty + 8 * j) * C + c0 + tx];
  __syncthreads();
#pragma unroll
  for (int j = 0; j < 4; ++j)
    out[(size_t)(c0 + ty + 8 * j) * R + r0 + tx] = f2bf(tile[tx][ty + 8 * j]);
}

// ---------------- elementwise / reductions ----------------

__global__ __launch_bounds__(256) void polynorm2_k(const float* __restrict__ lin,
                                                   us* __restrict__ outp) {
  __shared__ float red[256];
  int n = blockIdx.x, t = threadIdx.x;
  int rowp = cm_map(n);
  float s = 0.f;
  for (int f = t; f < 512; f += 256) { float v = lin[(size_t)n * 512 + f]; s += v * v; }
  float tot = block_reduce_sum(s, red);
  float sc = 1.0f / fmaxf(sqrtf(tot), 1e-12f);
  const float is2 = 0.70710678118654752f;
  for (int f = t; f < 512; f += 256) {
    float v = lin[(size_t)n * 512 + f] * sc;
    outp[(size_t)rowp * 1024 + f] = f2bf(v * is2);
    outp[(size_t)rowp * 1024 + 512 + f] = f2bf(v * v * is2);
  }
}

__global__ __launch_bounds__(256) void gates_k(const float* __restrict__ x,
    const float* __restrict__ wlr, const float* __restrict__ blr,
    const float* __restrict__ wmom, const float* __restrict__ bmom,
    const float* __restrict__ wdec, const float* __restrict__ bdec,
    const float* __restrict__ wgate, const float* __restrict__ bgate,
    float* __restrict__ lrv, float* __restrict__ momv,
    float* __restrict__ decv, float* __restrict__ og) {
  __shared__ float red[256];
  int n = blockIdx.x, t = threadIdx.x;
  float s0 = 0.f, s1 = 0.f, s2 = 0.f, s3 = 0.f;
  for (int d = t; d < 2048; d += 256) {
    float xv = x[(size_t)n * 2048 + d];
    s0 += xv * wlr[d]; s1 += xv * wmom[d]; s2 += xv * wdec[d]; s3 += xv * wgate[d];
  }
  float r0 = block_reduce_sum(s0, red);
  float r1 = block_reduce_sum(s1, red);
  float r2 = block_reduce_sum(s2, red);
  float r3 = block_reduce_sum(s3, red);
  if (t == 0) {
    lrv[n] = sigmoid_f(r0 + blr[0]);
    momv[n] = sigmoid_f(r1 + bmom[0]);
    decv[n] = sigmoid_f(r2 + bdec[0]);
    og[n] = sigmoid_f(r3 + bgate[0]);
  }
}

__global__ void chunk_means_k(const float* __restrict__ lrv, const float* __restrict__ momv,
                              const float* __restrict__ decv, float* __restrict__ cp) {
  int c = blockIdx.x, t = threadIdx.x;  // 64 threads
  int n = ((t >> 5) << 10) + c * 32 + (t & 31);
  float a = lrv[n], b = momv[n], d = decv[n];
  for (int off = 32; off > 0; off >>= 1) {
    a += __shfl_down(a, off);
    b += __shfl_down(b, off);
    d += __shfl_down(d, off);
  }
  if (t == 0) {
    cp[c * 3 + 0] = a * (1.f / 64.f);
    cp[c * 3 + 1] = b * (1.f / 64.f);
    cp[c * 3 + 2] = d * (1.f / 64.f);
  }
}

__global__ __launch_bounds__(256) void sampnorm2_k(const us* __restrict__ kp_b,
                                                   const float* __restrict__ dh,
                                                   const us* __restrict__ hab,
                                                   const us* __restrict__ pr,
                                                   float* __restrict__ w0inv,
                                                   float* __restrict__ w1inv, int c) {
  __shared__ float red[256];
  int i = blockIdx.x, t = threadIdx.x;
  int row = c * 64 + i;
  float sk = 0.f, sr = 0.f, sdh = 0.f, sa = 0.f;
  for (int p = t; p < 1024; p += 256) {
    float v = bf2f(kp_b[(size_t)row * 1024 + p]); sk += v * v;
    v = bf2f(pr[(size_t)(64 + i) * 1024 + p]); sr += v * v;
  }
  for (int h = t; h < 2048; h += 256) {
    float v = dh[(size_t)i * 2048 + h]; sdh += v * v;
    v = bf2f(hab[(size_t)(64 + i) * 2048 + h]); sa += v * v;
  }
  float tk = block_reduce_sum(sk, red);
  float tdh = block_reduce_sum(sdh, red);
  float ta = block_reduce_sum(sa, red);
  float tr = block_reduce_sum(sr, red);
  if (t == 0) {
    float n0 = fmaxf(sqrtf(tk) * sqrtf(tdh), 1e-8f);
    w0inv[i] = 1.0f / (64.0f * fmaxf(n0 * 0.1f, 1.0f));
    float n1 = fmaxf(sqrtf(ta) * sqrtf(tr), 1e-8f);
    w1inv[i] = 1.0f / (64.0f * fmaxf(n1 * 0.1f, 1.0f));
  }
}

__global__ __launch_bounds__(256) void frob2_k(const float* __restrict__ s0,
                                               const float* __restrict__ s1, int n,
                                               float* __restrict__ parts) {
  __shared__ float red[256];
  const float* s = blockIdx.z ? s1 : s0;
  float acc = 0.f;
  for (int i = blockIdx.x * 256 + threadIdx.x; i < n; i += gridDim.x * 256) {
    float v = s[i]; acc += v * v;
  }
  float r = block_reduce_sum(acc, red);
  if (threadIdx.x == 0) parts[blockIdx.z * 256 + blockIdx.x] = r;
}

__global__ __launch_bounds__(256) void frob_fin2_k(const float* __restrict__ parts,
                                                   float* __restrict__ inv) {
  __shared__ float red[256];
  float r = block_reduce_sum(parts[blockIdx.x * 256 + threadIdx.x], red);
  if (threadIdx.x == 0) inv[blockIdx.x] = 1.0f / (sqrtf(r) + 1e-7f);
}

__global__ void wupd0_k(float* __restrict__ W0, const us* __restrict__ X,
                        us* __restrict__ W0bT, const float* __restrict__ cp, int c) {
  __shared__ float tl[32][33];
  float lr = cp[c * 3 + 0], om = 1.0f - cp[c * 3 + 2];
  int c0 = blockIdx.x * 32, r0 = blockIdx.y * 32;
  int tx = threadIdx.x, ty = threadIdx.y;
#pragma unroll
  for (int j = 0; j < 4; ++j) {
    int r = r0 + ty + 8 * j, h = c0 + tx;
    size_t idx = (size_t)r * 2048 + h;
    float v = om * W0[idx] + lr * bf2f(X[idx]);
    W0[idx] = v;
    tl[ty + 8 * j][tx] = v;
  }
  __syncthreads();
#pragma unroll
  for (int j = 0; j < 4; ++j)
    W0bT[(size_t)(c0 + ty + 8 * j) * 1024 + r0 + tx] = f2bf(tl[tx][ty + 8 * j]);
}

__global__ void wupd1_k(float* __restrict__ W1, const us* __restrict__ X2,
                        us* __restrict__ W1b, us* __restrict__ W1bT,
                        const float* __restrict__ cp, int c) {
  __shared__ float tX[32][33];
  __shared__ float t2[32][33];
  float lr = cp[c * 3 + 0], om = 1.0f - cp[c * 3 + 2];
  int h0 = blockIdx.x * 32, p0 = blockIdx.y * 32;
  int tx = threadIdx.x, ty = threadIdx.y;
#pragma unroll
  for (int j = 0; j < 4; ++j)
    tX[ty + 8 * j][tx] = bf2f(X2[(size_t)(p0 + ty + 8 * j) * 2048 + h0 + tx]);
  __syncthreads();
#pragma unroll
  for (int j = 0; j < 4; ++j) {
    int h = h0 + ty + 8 * j, p = p0 + tx;
    size_t idx = (size_t)h * 1024 + p;
    float v = om * W1[idx] + lr * tX[tx][ty + 8 * j];
    W1[idx] = v;
    W1b[idx] = f2bf(v);
    t2[tx][ty + 8 * j] = v;
  }
  __syncthreads();
#pragma unroll
  for (int j = 0; j < 4; ++j)
    W1bT[(size_t)(p0 + ty + 8 * j) * 2048 + h0 + tx] = f2bf(t2[ty + 8 * j][tx]);
}

// ---------------- host ----------------

extern "C" void kernel_launch(void* const* d_in, const int* in_sizes, int n_in,
                              void* d_out, int out_size, void* d_ws, size_t ws_size,
                              hipStream_t stream) {
  const float* x = (const float*)d_in[0];
  const float* Wk = (const float*)d_in[1];
  const float* Wv = (const float*)d_in[2];
  const float* Wq = (const float*)d_in[3];
  const float* Wout = (const float*)d_in[4];
  const float* w_lr = (const float*)d_in[5];
  const float* b_lr = (const float*)d_in[6];
  const float* w_mom = (const float*)d_in[7];
  const float* b_mom = (const float*)d_in[8];
  const float* w_dec = (const float*)d_in[9];
  const float* b_dec = (const float*)d_in[10];
  const float* w_gate = (const float*)d_in[11];
  const float* b_gate = (const float*)d_in[12];
  const float* Wmem0 = (const float*)d_in[13];
  const float* Wmem1 = (const float*)d_in[14];
  const float* Wmemout = (const float*)d_in[15];
  const float* Wvexp = (const float*)d_in[16];
  float* out = (float*)d_out;
  (void)n_in; (void)in_sizes; (void)out_size;

  const long F = 1048576;
  const long BIG = 2097152;
  const long SB2 = 2097152, SB1 = 1048576;
  float* ws = (float*)d_ws;
  if (ws_size < (size_t)25043464 * sizeof(float)) return;

  us* kp_b   = (us*)ws;               // [0,1F)
  us* qp_b   = (us*)(ws + F);         // [1,2)
  float* vexp = ws + 2 * F;           // [2,4)
  float* W0  = ws + 4 * F;            // [4,6)
  float* W1  = ws + 6 * F;            // [6,8)
  float* S0  = ws + 8 * F;            // [8,10)
  float* S1  = ws + 10 * F;           // [10,12)
  us* XPong  = (us*)(ws + 12 * F);    // [12,14) pong packed X | Xfin rm | xb
  us* XTPong = (us*)(ws + 14 * F);    // [14,16) pong packed XT | Wkb/Wqb/Wvb
  us* XPing  = (us*)(ws + 16 * F);    // [16,18) ping packed X | vlin/WvexpT
  us* AP     = (us*)(ws + 18 * F);    // [18,19) packed A | Woutb (final)
  float* SCR = ws + 19 * F;           // [19,20) chunk scratch
  us* XTPing = (us*)(ws + 20 * F);    // [20,22) ping packed XT (= W0bT/W1bT)
  us* BP     = (us*)(ws + 22 * F);    // [22,23) packed B (= W1b)
  us* W0bT   = (us*)(ws + 20 * F);    // chunk-path alias (regenerated by wupd0)
  us* W1bT   = (us*)(ws + 21 * F);
  us* W1b    = (us*)(ws + 22 * F);
  us* WmoT   = (us*)(ws + 23 * F);    // [23,23.25)
  us* retrv  = (us*)(ws + 23 * F + 262144);
  float* smal = ws + 23 * F + 262144 + 524288;
  float* og   = smal;
  float* lrv  = og + 2048;
  float* momv = lrv + 2048;
  float* decv = momv + 2048;
  float* cpb  = decv + 2048;
  float* w0inv = cpb + 128;
  float* w1inv = w0inv + 64;
  float* parts = w1inv + 64;
  float* inv01 = parts + 512;

  us* xb   = XPong;                    // prologue aliases
  us* Wkb  = XTPong;
  us* Wqb  = XTPong + 1048576;
  us* Wvb  = XTPong + 2097152;
  us* vlin = XPing;
  us* WvexpT = XPing + 1048576;
  us* Woutb = AP;
  float* lin = SCR;
  us* hab   = (us*)SCR;
  float* gp = SCR + 131072;
  us* pr    = (us*)(SCR + 262144);
  float* dh = SCR + 327680;
  us* dhT   = (us*)(SCR + 458752);
  us* rbwT  = (us*)(SCR + 524288);
  us* Xfin  = XPong;                   // final NS output rm [2][1024][2048]

  const float NSa = 3.4445f, NSb = -4.7750f, NSc = 2.0315f;

  hipMemcpyAsync(W0, Wmem0, (size_t)BIG * 4, hipMemcpyDeviceToDevice, stream);
  hipMemcpyAsync(W1, Wmem1, (size_t)BIG * 4, hipMemcpyDeviceToDevice, stream);
  hipMemsetAsync(S0, 0, (size_t)BIG * 4, stream);
  hipMemsetAsync(S1, 0, (size_t)BIG * 4, stream);
  hipLaunchKernelGGL(tconv_k, dim3(64, 32), dim3(32, 8), 0, stream, Wmem0, W0bT, 1024, 2048);
  hipLaunchKernelGGL(conv_k, dim3(1024), dim3(256), 0, stream, Wmem1, W1b, (int)BIG);
  hipLaunchKernelGGL(tconv_k, dim3(32, 64), dim3(32, 8), 0, stream, Wmem1, W1bT, 2048, 1024);
  hipLaunchKernelGGL(tconv_k, dim3(16, 32), dim3(32, 8), 0, stream, Wmemout, WmoT, 1024, 512);
  hipLaunchKernelGGL(tconv_k, dim3(32, 16), dim3(32, 8), 0, stream, Wvexp, WvexpT, 512, 1024);
  hipLaunchKernelGGL(conv_k, dim3(2048), dim3(256), 0, stream, x, xb, 2048 * 2048);
  hipLaunchKernelGGL(conv_k, dim3(512), dim3(256), 0, stream, Wk, Wkb, 512 * 2048);
  hipLaunchKernelGGL(conv_k, dim3(512), dim3(256), 0, stream, Wq, Wqb, 512 * 2048);
  hipLaunchKernelGGL(conv_k, dim3(512), dim3(256), 0, stream, Wv, Wvb, 512 * 2048);

  mg<7>(stream, xb, nullptr, Wkb, lin, nullptr, nullptr, nullptr, nullptr, nullptr, 0,
        2048, 512, 2048, 2048, 2048, 512, 0);
  hipLaunchKernelGGL(polynorm2_k, dim3(2048), dim3(256), 0, stream, lin, kp_b);
  mg<7>(stream, xb, nullptr, Wqb, lin, nullptr, nullptr, nullptr, nullptr, nullptr, 0,
        2048, 512, 2048, 2048, 2048, 512, 0);
  hipLaunchKernelGGL(polynorm2_k, dim3(2048), dim3(256), 0, stream, lin, qp_b);
  mg<5>(stream, xb, nullptr, Wvb, vlin, nullptr, nullptr, nullptr, nullptr, nullptr, 0,
        2048, 512, 2048, 2048, 2048, 512, 0);
  mg<17>(stream, vlin, nullptr, WvexpT, vexp, nullptr, nullptr, nullptr, nullptr, nullptr, 0,
         2048, 1024, 512, 512, 512, 1024, 0);

  hipLaunchKernelGGL(gates_k, dim3(2048), dim3(256), 0, stream, x,
                     w_lr, b_lr, w_mom, b_mom, w_dec, b_dec, w_gate, b_gate,
                     lrv, momv, decv, og);
  hipLaunchKernelGGL(chunk_means_k, dim3(32), dim3(64), 0, stream, lrv, momv, decv, cpb);

  for (int c = 0; c < 32; ++c) {
    const us* kp_c = kp_b + (size_t)c * 64 * 1024;
    const us* qp_c = qp_b + (size_t)c * 64 * 1024;
    const float* vexp_c = vexp + (size_t)c * 64 * 1024;
    mg<8, 0, 1>(stream, qp_c, kp_c, W0bT, hab, gp, nullptr, nullptr, nullptr, nullptr, 0,
                128, 2048, 1024, 1024, 1024, 2048, 0);
    mg<9>(stream, hab, nullptr, W1bT, pr, nullptr, vexp_c, nullptr, nullptr, nullptr, 0,
          128, 1024, 2048, 2048, 2048, 1024, 1024);
    mg<5>(stream, pr, nullptr, WmoT, retrv + (size_t)c * 64 * 512, nullptr, nullptr,
          nullptr, nullptr, nullptr, 0, 64, 512, 1024, 1024, 1024, 512, 0);
    mg<13>(stream, pr + 64 * 1024, nullptr, W1b, dh, nullptr, gp, nullptr, nullptr, nullptr, 0,
           64, 2048, 1024, 1024, 1024, 2048, 2048);
    hipLaunchKernelGGL(sampnorm2_k, dim3(64), dim3(256), 0, stream,
                       kp_b, dh, hab, pr, w0inv, w1inv, c);
    hipLaunchKernelGGL(wt2_k, dim3(192), dim3(32, 8), 0, stream,
                       dh, w0inv, dhT, pr + 64 * 1024, w1inv, rbwT);
    hipLaunchKernelGGL(mg2_k, dim3(1024), dim3(64), 0, stream,
                       kp_c, dhT, S0, hab + 64 * 2048, rbwT, S1, cpb, c);

    // ---- batched NS5: batch0 = S0 (1024x2048), batch1 = S1^T ----
    hipLaunchKernelGGL(frob2_k, dim3(256, 1, 2), dim3(256), 0, stream, S0, S1, (int)BIG, parts);
    hipLaunchKernelGGL(frob_fin2_k, dim3(2), dim3(256), 0, stream, parts, inv01);
    hipLaunchKernelGGL(scalepk2_k, dim3(64, 32, 2), dim3(32, 8), 0, stream,
                       S0, S1, inv01, XPing, XTPing);

    us* xpA[2] = {XPing, XPong};
    us* xtA[2] = {XTPing, XTPong};
    int cur = 0;
    for (int it = 0; it < 5; ++it) {
      const us* XPc = xpA[cur];
      const us* XTPc = xtA[cur];
      int nxt = cur ^ 1;
      // AP = pack(Xc @ Xc^T)  (full 8x8 tile grid, K=2048)
      mgp<20, 8, 8>(stream, XPc, XPc, AP, nullptr, nullptr, 2048, 1024,
                    0.f, 0.f, SB2, SB2, SB1, 0);
      // BP = pack(NSc*(A@A) + NSb*A)  (K=1024)
      mgp<21, 8, 8>(stream, AP, AP, BP, nullptr, AP, 1024, 1024,
                    NSc, NSb, SB1, SB1, SB1, SB1);
      if (it < 4) {
        // XPn/XTn = pack(B@Xc + NSa*Xc)
        mgp<23, 8, 16>(stream, BP, XTPc, xpA[nxt], xtA[nxt], XPc, 1024, 2048,
                       NSa, 0.f, SB1, SB2, SB2, SB2);
        cur = nxt;
      } else {
        // Xfin (row-major) = B@Xc + NSa*Xc
        mgp<24, 8, 16>(stream, BP, XTPc, Xfin, nullptr, XPc, 1024, 2048,
                       NSa, 0.f, SB1, SB2, SB2, SB2);
      }
    }
    hipLaunchKernelGGL(wupd0_k, dim3(64, 32), dim3(32, 8), 0, stream, W0, Xfin, W0bT, cpb, c);
    hipLaunchKernelGGL(wupd1_k, dim3(64, 32), dim3(32, 8), 0, stream, W1, Xfin + SB2, W1b, W1bT, cpb, c);
  }

  hipLaunchKernelGGL(conv_k, dim3(1024), dim3(256), 0, stream, Wout, Woutb, 2048 * 512);
  mg<15, 0, 0, 1>(stream, retrv, nullptr, Woutb, out, nullptr, nullptr, x, og, nullptr, 0,
                  2048, 2048, 512, 512, 512, 2048, 0);
}

// Round 18
// 14305.586 us; speedup vs baseline: 1.1904x; 1.0726x over previous
//
#include <hip/hip_runtime.h>

// ---------------------------------------------------------------------------
// DeepMemoryLevel (ATLAS-style). B=2 S=1024 D=2048 M=512 P=1024 H=2048
// CHUNK=32 NC=32, tokens N=2048.
// Round 18: R17 + (a) Frobenius reduction fused into mg2's epilogue
// (per-block partials, deterministic wave reduce; frob2 pass deleted);
// (b) G3+G4 merged into one 40-block launch; (c) wupd0+wupd1 merged (z=2).
// Launches/chunk 27 -> 24. NS GEMMs unchanged (R15 4-wave 128x128 packed).
// ---------------------------------------------------------------------------

typedef unsigned short us;
typedef __attribute__((ext_vector_type(8))) short s16x8;
typedef __attribute__((ext_vector_type(8))) unsigned short u16x8;
typedef __attribute__((ext_vector_type(4))) float f32x4;

#define MKP 72

__device__ __forceinline__ float gelu_f(float x) {
  return 0.5f * x * (1.0f + erff(x * 0.70710678118654752f));
}
__device__ __forceinline__ float gelu_grad_f(float x) {
  float cdf = 0.5f * (1.0f + erff(x * 0.70710678118654752f));
  float pdf = 0.3989422804014327f * expf(-0.5f * x * x);
  return cdf + x * pdf;
}
__device__ __forceinline__ float sigmoid_f(float x) { return 1.0f / (1.0f + expf(-x)); }

__device__ __forceinline__ us f2bf(float f) {
  union { float f; unsigned u; } v; v.f = f;
  unsigned r = (v.u + 0x7FFFu + ((v.u >> 16) & 1u)) >> 16;
  return (us)r;
}
__device__ __forceinline__ float bf2f(us h) {
  union { unsigned u; float f; } v; v.u = ((unsigned)h) << 16;
  return v.f;
}
// token-major index n -> chunk-major row
__device__ __forceinline__ int cm_map(int n) {
  return ((n & 1023) >> 5) * 64 + (n >> 10) * 32 + (n & 31);
}
// packed-fragment offset: matrix R x K (row-major source), element (r,k).
__device__ __forceinline__ size_t pf_off(int r, int k, int KB) {
  return ((size_t)(r >> 4) * KB + (k >> 5)) * 512 + ((k >> 3) & 3) * 128 + (r & 15) * 8 + (k & 7);
}

__device__ __forceinline__ float block_reduce_sum(float v, float* red) {
  int t = threadIdx.x;
  red[t] = v; __syncthreads();
  for (int s = blockDim.x >> 1; s > 0; s >>= 1) {
    if (t < s) red[t] += red[t + s];
    __syncthreads();
  }
  float r = red[0];
  __syncthreads();
  return r;
}

// ---------------- packed-fragment GEMM core (R12-proven) ----------------
__device__ __forceinline__ void gemm_pk(const us* __restrict__ A,
                                        const us* __restrict__ B, int KB,
                                        int lane, int m0, int n0,
                                        f32x4 (&acc)[4][4]) {
  const us* am[4];
  const us* bm[4];
#pragma unroll
  for (int q = 0; q < 4; ++q) {
    am[q] = A + (size_t)((m0 >> 4) + q) * KB * 512 + lane * 8;
    bm[q] = B + (size_t)((n0 >> 4) + q) * KB * 512 + lane * 8;
  }
#pragma unroll
  for (int i = 0; i < 4; ++i)
#pragma unroll
    for (int j = 0; j < 4; ++j) acc[i][j] = (f32x4){0.f, 0.f, 0.f, 0.f};
  u16x8 a0[4], b0[4], a1[4], b1[4];
#pragma unroll
  for (int q = 0; q < 4; ++q) {
    a0[q] = *(const u16x8*)(am[q]);
    b0[q] = *(const u16x8*)(bm[q]);
    a1[q] = *(const u16x8*)(am[q] + 512);
    b1[q] = *(const u16x8*)(bm[q] + 512);
  }
  for (int kb = 0; kb < KB; kb += 2) {
#pragma unroll
    for (int mi = 0; mi < 4; ++mi)
#pragma unroll
      for (int ni = 0; ni < 4; ++ni)
        acc[mi][ni] = __builtin_amdgcn_mfma_f32_16x16x32_bf16(
            (s16x8)a0[mi], (s16x8)b0[ni], acc[mi][ni], 0, 0, 0);
    if (kb + 2 < KB) {
#pragma unroll
      for (int q = 0; q < 4; ++q) {
        a0[q] = *(const u16x8*)(am[q] + (size_t)(kb + 2) * 512);
        b0[q] = *(const u16x8*)(bm[q] + (size_t)(kb + 2) * 512);
      }
    }
#pragma unroll
    for (int mi = 0; mi < 4; ++mi)
#pragma unroll
      for (int ni = 0; ni < 4; ++ni)
        acc[mi][ni] = __builtin_amdgcn_mfma_f32_16x16x32_bf16(
            (s16x8)a1[mi], (s16x8)b1[ni], acc[mi][ni], 0, 0, 0);
    if (kb + 3 < KB) {
#pragma unroll
      for (int q = 0; q < 4; ++q) {
        a1[q] = *(const u16x8*)(am[q] + (size_t)(kb + 3) * 512);
        b1[q] = *(const u16x8*)(bm[q] + (size_t)(kb + 3) * 512);
      }
    }
  }
}

// ---------------- 4-wave 128x128 packed MFMA GEMM (barrier-free) ----------
// EPI 20: C packed (KC = N>>5).
// EPI 21: C packed = c1*acc + c2*E_packed.
// EPI 23: X-update it<4: o = acc + c1*E(XPc packed KB=64);
//         C=XPn packed (KB=64), C2=XTPn packed ([2048][1024], KB=32).
// EPI 24: X-update it=4: o = acc + c1*E(packed KB=64); C row-major ldc=2048.
template<int EPI, int TM, int TN>
__global__ __launch_bounds__(256)
void mgp_k(const us* __restrict__ Aq, const us* __restrict__ Bq,
           us* __restrict__ Cq, us* __restrict__ C2q, const us* __restrict__ Eq,
           int K, int N, float c1, float c2,
           long sA, long sB, long sC, long sE) {
  __shared__ __align__(16) us ct[4 * 64 * 72];
  const int tid = threadIdx.x;
  const int wave = tid >> 6, lane = tid & 63;
  const int l15 = lane & 15, l4 = lane >> 4;
  const int wm = (wave >> 1) * 64, wn = (wave & 1) * 64;
  const int TPB = TM * TN;
  const int t = blockIdx.x;
  const int bz = t / TPB;
  const int ti = t - bz * TPB;
  const int m0 = (ti / TN) * 128 + wm;
  const int n0 = (ti % TN) * 128 + wn;

  const us* A = Aq + (size_t)bz * sA;
  const us* B = Bq + (size_t)bz * sB;
  us* C = Cq + (size_t)bz * sC;
  us* C2 = C2q + (size_t)bz * sC;
  const us* E = Eq + (size_t)bz * sE;
  const int KB = K >> 5;

  f32x4 acc[4][4];
  gemm_pk(A, B, KB, lane, m0, n0, acc);

  us* cw = ct + wave * 64 * 72;
#pragma unroll
  for (int mi = 0; mi < 4; ++mi)
#pragma unroll
    for (int i = 0; i < 4; ++i)
#pragma unroll
      for (int ni = 0; ni < 4; ++ni)
        cw[(mi * 16 + l4 * 4 + i) * 72 + ni * 16 + l15] = f2bf(acc[mi][ni][i]);

  if constexpr (EPI == 20 || EPI == 21) {
    const int KC = N >> 5;
#pragma unroll
    for (int q = 0; q < 8; ++q) {
      u16x8 v = *(const u16x8*)&cw[lane * 72 + q * 8];
      size_t off = pf_off(m0 + lane, n0 + q * 8, KC);
      if constexpr (EPI == 21) {
        u16x8 e = *(const u16x8*)(E + off);
        u16x8 o;
#pragma unroll
        for (int w = 0; w < 8; ++w) o[w] = f2bf(c1 * bf2f(v[w]) + c2 * bf2f(e[w]));
        *(u16x8*)(C + off) = o;
      } else {
        *(u16x8*)(C + off) = v;
      }
    }
  } else if constexpr (EPI == 23) {
#pragma unroll
    for (int q = 0; q < 8; ++q) {
      size_t off = pf_off(m0 + lane, n0 + q * 8, 64);
      u16x8 v = *(const u16x8*)&cw[lane * 72 + q * 8];
      u16x8 e = *(const u16x8*)(E + off);
      u16x8 o;
#pragma unroll
      for (int w = 0; w < 8; ++w) o[w] = f2bf(bf2f(v[w]) + c1 * bf2f(e[w]));
      *(u16x8*)&cw[lane * 72 + q * 8] = o;
      *(u16x8*)(C + off) = o;
    }
#pragma unroll
    for (int q = 0; q < 8; ++q) {
      u16x8 o;
#pragma unroll
      for (int w = 0; w < 8; ++w) o[w] = cw[(q * 8 + w) * 72 + lane];
      size_t offT = pf_off(n0 + lane, m0 + q * 8, 32);
      *(u16x8*)(C2 + offT) = o;
    }
  } else {  // EPI 24
#pragma unroll
    for (int q = 0; q < 8; ++q) {
      size_t off = pf_off(m0 + lane, n0 + q * 8, 64);
      u16x8 v = *(const u16x8*)&cw[lane * 72 + q * 8];
      u16x8 e = *(const u16x8*)(E + off);
      u16x8 o;
#pragma unroll
      for (int w = 0; w < 8; ++w) o[w] = f2bf(bf2f(v[w]) + c1 * bf2f(e[w]));
      *(u16x8*)(C + (size_t)(m0 + lane) * 2048 + n0 + q * 8) = o;
    }
  }
}

template<int EPI, int TM, int TN>
static void mgp(hipStream_t st, const us* A, const us* B, us* C, us* C2,
                const us* E, int K, int N, float c1, float c2,
                long sA, long sB, long sC, long sE) {
  dim3 g(TM * TN * 2), b(256);
  hipLaunchKernelGGL((mgp_k<EPI, TM, TN>), g, b, 0, st, A, B, C, C2, E,
                     K, N, c1, c2, sA, sB, sC, sE);
}

// ---------------- epilogue for LDS GEMM (chunk path) ----------------
// Returns sum of v^2 (EPI 14 only; 0 otherwise) for fused Frobenius.
template<int EPI>
__device__ __forceinline__ float epilogue(f32x4 (&acc)[4][4], int m0, int n0,
    int l15, int l4, void* Cq, void* C2, const void* Eq,
    const float* FX, const float* OG, const float* cp, int cidx,
    int ldc, int lde, float c1, float c2) {
  float ssq = 0.f;
#pragma unroll
  for (int mi = 0; mi < 4; ++mi) {
#pragma unroll
    for (int i = 0; i < 4; ++i) {
      int grow = m0 + mi * 16 + l4 * 4 + i;
#pragma unroll
      for (int ni = 0; ni < 4; ++ni) {
        int col = n0 + ni * 16 + l15;
        float v = acc[mi][ni][i];
        if constexpr (EPI == 5) {
          ((us*)Cq)[(size_t)grow * ldc + col] = f2bf(v);
        } else if constexpr (EPI == 7) {
          ((float*)Cq)[(size_t)grow * ldc + col] = v;
        } else if constexpr (EPI == 8) {
          ((us*)Cq)[(size_t)grow * ldc + col] = f2bf(gelu_f(v));
          if (m0 >= 64)
            ((float*)C2)[(size_t)(grow - 64) * ldc + col] = gelu_grad_f(v);
        } else if constexpr (EPI == 9) {
          if (m0 < 64)
            ((us*)Cq)[(size_t)grow * ldc + col] = f2bf(v);
          else
            ((us*)Cq)[(size_t)grow * ldc + col] =
                f2bf(2.0f * (v - ((const float*)Eq)[(size_t)(grow - 64) * lde + col]));
        } else if constexpr (EPI == 13) {
          ((float*)Cq)[(size_t)grow * ldc + col] =
              v * ((const float*)Eq)[(size_t)grow * lde + col];
        } else if constexpr (EPI == 14) {
          float* C = (float*)Cq;
          float old = C[(size_t)grow * ldc + col];
          float nv = cp[cidx * 3 + 1] * old - cp[cidx * 3 + 0] * v;
          C[(size_t)grow * ldc + col] = nv;
          ssq += nv * nv;
        } else if constexpr (EPI == 15) {
          ((float*)Cq)[(size_t)grow * ldc + col] =
              FX[(size_t)grow * ldc + col] + v * OG[grow];
        } else if constexpr (EPI == 17) {
          int crow = cm_map(grow);
          ((float*)Cq)[(size_t)crow * ldc + col] = v;
        }
      }
    }
  }
  return ssq;
}

// ---------------- 1-wave 64x64 LDS GEMM body (chunk path) ----------------
template<int EPI, int TA, int DUAL, int AG>
__device__ __forceinline__ float mg_body(const us* __restrict__ A0,
    const us* __restrict__ A2, const us* __restrict__ B,
    void* __restrict__ Cq, void* __restrict__ C2, const void* __restrict__ Eq,
    const float* __restrict__ FX, const float* __restrict__ OG,
    const float* __restrict__ cp, int cidx, int m0, int n0,
    int K, int lda, int ldb, int ldc, int lde, float c1, float c2,
    us* As, us* Bs, int t) {
  const us* A = A0;
  if constexpr (DUAL) { if (m0 >= 64) A = A2; }
  const int mA0 = DUAL ? (m0 & 63) : m0;
  const int l15 = t & 15, l4 = t >> 4;

  f32x4 acc[4][4];
#pragma unroll
  for (int i = 0; i < 4; ++i)
#pragma unroll
    for (int j = 0; j < 4; ++j) acc[i][j] = (f32x4){0.f, 0.f, 0.f, 0.f};

  const int srw = t >> 3;
  const int sck = (t & 7) * 8;

  u16x8 ra[8], rb[8];
  auto LDA = [&](int k0) {
#pragma unroll
    for (int p = 0; p < 8; ++p) {
      if constexpr (TA == 0) {
        int row = srw + p * 8;
        int srow;
        if constexpr (AG) srow = cm_map(m0 + row); else srow = mA0 + row;
        ra[p] = *(const u16x8*)(A + (size_t)srow * lda + k0 + sck);
      } else {
        ra[p] = *(const u16x8*)(A + (size_t)(k0 + srw + p * 8) * lda + mA0 + sck);
      }
    }
  };
  auto LDB = [&](int k0) {
#pragma unroll
    for (int p = 0; p < 8; ++p)
      rb[p] = *(const u16x8*)(B + (size_t)(n0 + srw + p * 8) * ldb + k0 + sck);
  };

  LDA(0); LDB(0);
  for (int k0 = 0; k0 < K; k0 += 64) {
    if constexpr (TA == 0) {
#pragma unroll
      for (int p = 0; p < 8; ++p)
        *(u16x8*)&As[(srw + p * 8) * MKP + sck] = ra[p];
    } else {
#pragma unroll
      for (int p = 0; p < 8; ++p) {
        int kk = srw + p * 8;
#pragma unroll
        for (int j = 0; j < 8; ++j) As[(sck + j) * MKP + kk] = ra[p][j];
      }
    }
#pragma unroll
    for (int p = 0; p < 8; ++p)
      *(u16x8*)&Bs[(srw + p * 8) * MKP + sck] = rb[p];
    if (k0 + 64 < K) { LDA(k0 + 64); LDB(k0 + 64); }
#pragma unroll
    for (int ks = 0; ks < 2; ++ks) {
      s16x8 af[4], bf[4];
#pragma unroll
      for (int mi = 0; mi < 4; ++mi)
        af[mi] = *(const s16x8*)&As[(mi * 16 + l15) * MKP + ks * 32 + l4 * 8];
#pragma unroll
      for (int ni = 0; ni < 4; ++ni)
        bf[ni] = *(const s16x8*)&Bs[(ni * 16 + l15) * MKP + ks * 32 + l4 * 8];
#pragma unroll
      for (int mi = 0; mi < 4; ++mi)
#pragma unroll
        for (int ni = 0; ni < 4; ++ni)
          acc[mi][ni] = __builtin_amdgcn_mfma_f32_16x16x32_bf16(af[mi], bf[ni], acc[mi][ni], 0, 0, 0);
    }
  }

  return epilogue<EPI>(acc, m0, n0, l15, l4, Cq, C2, Eq, FX, OG, cp, cidx,
                       ldc, lde, c1, c2);
}

template<int EPI, int TA, int DUAL, int AG>
__global__ __launch_bounds__(64)
void mg_k(const us* __restrict__ Aq, const us* __restrict__ A2,
          const us* __restrict__ Bq, void* __restrict__ Cq,
          void* __restrict__ C2, const void* __restrict__ Eq,
          const float* __restrict__ FX, const float* __restrict__ OG,
          const float* __restrict__ cp, int cidx,
          int M, int N, int K, int lda, int ldb, int ldc, int lde,
          float c1, float c2) {
  __shared__ __align__(16) us As[64 * MKP];
  __shared__ __align__(16) us Bs[64 * MKP];
  mg_body<EPI, TA, DUAL, AG>(Aq, A2, Bq, Cq, C2, Eq, FX, OG, cp, cidx,
                             blockIdx.y * 64, blockIdx.x * 64, K, lda, ldb,
                             ldc, lde, c1, c2, As, Bs, threadIdx.x);
}

template<int EPI, int TA = 0, int DUAL = 0, int AG = 0>
static void mg(hipStream_t st, const us* A, const us* A2, const us* B,
               void* C, void* C2, const void* E,
               const float* FX, const float* OG, const float* cp, int cidx,
               int M, int N, int K, int lda, int ldb, int ldc, int lde,
               float c1 = 0.f, float c2 = 0.f) {
  dim3 g(N / 64, M / 64, 1), b(64);
  hipLaunchKernelGGL((mg_k<EPI, TA, DUAL, AG>), g, b, 0, st, A, A2, B, C, C2, E,
                     FX, OG, cp, cidx, M, N, K, lda, ldb, ldc, lde, c1, c2);
}

// ---- merged G5+G6 (EPI 14, TA=1) + fused Frobenius partials: 1024 blocks ----
__global__ __launch_bounds__(64)
void mg2_k(const us* __restrict__ kp_c, const us* __restrict__ dhT,
           float* __restrict__ S0, const us* __restrict__ habk,
           const us* __restrict__ rbwT, float* __restrict__ S1,
           const float* __restrict__ cp, int c, float* __restrict__ parts2) {
  __shared__ __align__(16) us As[64 * MKP];
  __shared__ __align__(16) us Bs[64 * MKP];
  int bid = blockIdx.x;
  float ssq;
  if (bid < 512) {
    int m0 = (bid >> 5) * 64, n0 = (bid & 31) * 64;   // M=1024, N=2048
    ssq = mg_body<14, 1, 0, 0>(kp_c, nullptr, dhT, S0, nullptr, nullptr,
                               nullptr, nullptr, cp, c, m0, n0,
                               64, 1024, 64, 2048, 0, 0.f, 0.f, As, Bs, threadIdx.x);
  } else {
    int b2 = bid - 512;
    int m0 = (b2 >> 4) * 64, n0 = (b2 & 15) * 64;     // M=2048, N=1024
    ssq = mg_body<14, 1, 0, 0>(habk, nullptr, rbwT, S1, nullptr, nullptr,
                               nullptr, nullptr, cp, c, m0, n0,
                               64, 2048, 64, 1024, 0, 0.f, 0.f, As, Bs, threadIdx.x);
  }
  // deterministic wave reduce (fixed shuffle order)
  for (int off = 32; off > 0; off >>= 1) ssq += __shfl_down(ssq, off);
  if (threadIdx.x == 0) parts2[bid] = ssq;
}

// ---- merged G3+G4: 40 blocks 1D ----
__global__ __launch_bounds__(64)
void mg34_k(const us* __restrict__ pr, const us* __restrict__ WmoT,
            us* __restrict__ retrv_c, const us* __restrict__ W1b,
            float* __restrict__ dh, const float* __restrict__ gp) {
  __shared__ __align__(16) us As[64 * MKP];
  __shared__ __align__(16) us Bs[64 * MKP];
  int bid = blockIdx.x;
  if (bid < 8) {
    // G3: pred@WmoT -> retrv (64x512, K=1024)
    mg_body<5, 0, 0, 0>(pr, nullptr, WmoT, retrv_c, nullptr, nullptr,
                        nullptr, nullptr, nullptr, 0, 0, bid * 64,
                        1024, 1024, 1024, 512, 0, 0.f, 0.f, As, Bs, threadIdx.x);
  } else {
    int b2 = bid - 8;
    // G4: r@W1b * gelu' -> dh (64x2048, K=1024)
    mg_body<13, 0, 0, 0>(pr + 64 * 1024, nullptr, W1b, dh, nullptr, gp,
                         nullptr, nullptr, nullptr, 0, 0, b2 * 64,
                         1024, 1024, 1024, 2048, 2048, 0.f, 0.f, As, Bs, threadIdx.x);
  }
}

// ---------------- merged wtrans pair: 192 blocks 1D, block (32,8) -----------
__global__ void wt2_k(const float* __restrict__ dh, const float* __restrict__ w0inv,
                      us* __restrict__ dhT, const us* __restrict__ prg,
                      const float* __restrict__ w1inv, us* __restrict__ rbwT) {
  __shared__ float tile[32][33];
  int bid = blockIdx.x;
  int tx = threadIdx.x, ty = threadIdx.y;
  int c0, r0, ldin;
  const float* wv;
  us* outp;
  bool f32in;
  const void* in;
  if (bid < 128) {
    in = dh; wv = w0inv; outp = dhT; ldin = 2048; f32in = true;
    c0 = (bid & 63) * 32; r0 = (bid >> 6) * 32;
  } else {
    int b2 = bid - 128;
    in = prg; wv = w1inv; outp = rbwT; ldin = 1024; f32in = false;
    c0 = (b2 & 31) * 32; r0 = (b2 >> 5) * 32;
  }
#pragma unroll
  for (int j = 0; j < 4; ++j) {
    int r = r0 + ty + 8 * j, cc = c0 + tx;
    float v = f32in ? ((const float*)in)[(size_t)r * ldin + cc]
                    : bf2f(((const us*)in)[(size_t)r * ldin + cc]);
    tile[ty + 8 * j][tx] = v * wv[r];
  }
  __syncthreads();
#pragma unroll
  for (int j = 0; j < 4; ++j)
    outp[(size_t)(c0 + ty + 8 * j) * 64 + r0 + tx] = f2bf(tile[tx][ty + 8 * j]);
}

// ---------------- scale + pack (merged, z=2): S -> XP + XTP packed -----------
__global__ void scalepk2_k(const float* __restrict__ S0, const float* __restrict__ S1,
                           const float* __restrict__ inv01,
                           us* __restrict__ XP, us* __restrict__ XTP) {
  __shared__ float tile[32][33];
  const long SB2c = 2097152;
  int z = blockIdx.z;
  float s = inv01[z];
  int tx = threadIdx.x, ty = threadIdx.y;  // 32 x 8
  int r0, c0;
  const float* S;
  if (z == 0) { S = S0; c0 = blockIdx.x * 32; r0 = blockIdx.y * 32; }
  else        { S = S1; r0 = blockIdx.x * 32; c0 = blockIdx.y * 32; }
  int C = (z == 0) ? 2048 : 1024;
#pragma unroll
  for (int j = 0; j < 4; ++j)
    tile[ty + 8 * j][tx] = S[(size_t)(r0 + ty + 8 * j) * C + c0 + tx] * s;
  __syncthreads();
  us* xp = XP + (size_t)z * SB2c;
  us* xt = XTP + (size_t)z * SB2c;
  int t = ty * 32 + tx;
  if (t < 128) {
    int rh = t >> 2, cc = t & 3;
    u16x8 v;
#pragma unroll
    for (int e = 0; e < 8; ++e) v[e] = f2bf(tile[rh][cc * 8 + e]);
    if (z == 0) {
      *(u16x8*)(xp + pf_off(r0 + rh, c0 + cc * 8, 64)) = v;
    } else {
      *(u16x8*)(xt + pf_off(r0 + rh, c0 + cc * 8, 32)) = v;
    }
  } else {
    int ch = (t - 128) >> 2, rc = (t - 128) & 3;
    u16x8 v;
#pragma unroll
    for (int e = 0; e < 8; ++e) v[e] = f2bf(tile[rc * 8 + e][ch]);
    if (z == 0) {
      *(u16x8*)(xt + pf_off(c0 + ch, r0 + rc * 8, 32)) = v;
    } else {
      *(u16x8*)(xp + pf_off(c0 + ch, r0 + rc * 8, 64)) = v;
    }
  }
}

// ---------------- conversions ----------------

__global__ __launch_bounds__(256) void conv_k(const float* __restrict__ in,
                                              us* __restrict__ out, int n) {
  for (int i = blockIdx.x * 256 + threadIdx.x; i < n; i += gridDim.x * 256)
    out[i] = f2bf(in[i]);
}

__global__ void tconv_k(const float* __restrict__ in, us* __restrict__ out, int R, int C) {
  __shared__ float tile[32][33];
  int c0 = blockIdx.x * 32, r0 = blockIdx.y * 32;
  int tx = threadIdx.x, ty = threadIdx.y;
#pragma unroll
  for (int j = 0; j < 4; ++j)
    tile[ty + 8 * j][tx] = in[(size_t)(r0 + ty + 8 * j) * C + c0 + tx];
  __syncthreads();
#pragma unroll
  for (int j = 0; j < 4; ++j)
    out[(size_t)(c0 + ty + 8 * j) * R + r0 + tx] = f2bf(tile[tx][ty + 8 * j]);
}

// ---------------- elementwise / reductions ----------------

__global__ __launch_bounds__(256) void polynorm2_k(const float* __restrict__ lin,
                                                   us* __restrict__ outp) {
  __shared__ float red[256];
  int n = blockIdx.x, t = threadIdx.x;
  int rowp = cm_map(n);
  float s = 0.f;
  for (int f = t; f < 512; f += 256) { float v = lin[(size_t)n * 512 + f]; s += v * v; }
  float tot = block_reduce_sum(s, red);
  float sc = 1.0f / fmaxf(sqrtf(tot), 1e-12f);
  const float is2 = 0.70710678118654752f;
  for (int f = t; f < 512; f += 256) {
    float v = lin[(size_t)n * 512 + f] * sc;
    outp[(size_t)rowp * 1024 + f] = f2bf(v * is2);
    outp[(size_t)rowp * 1024 + 512 + f] = f2bf(v * v * is2);
  }
}

__global__ __launch_bounds__(256) void gates_k(const float* __restrict__ x,
    const float* __restrict__ wlr, const float* __restrict__ blr,
    const float* __restrict__ wmom, const float* __restrict__ bmom,
    const float* __restrict__ wdec, const float* __restrict__ bdec,
    const float* __restrict__ wgate, const float* __restrict__ bgate,
    float* __restrict__ lrv, float* __restrict__ momv,
    float* __restrict__ decv, float* __restrict__ og) {
  __shared__ float red[256];
  int n = blockIdx.x, t = threadIdx.x;
  float s0 = 0.f, s1 = 0.f, s2 = 0.f, s3 = 0.f;
  for (int d = t; d < 2048; d += 256) {
    float xv = x[(size_t)n * 2048 + d];
    s0 += xv * wlr[d]; s1 += xv * wmom[d]; s2 += xv * wdec[d]; s3 += xv * wgate[d];
  }
  float r0 = block_reduce_sum(s0, red);
  float r1 = block_reduce_sum(s1, red);
  float r2 = block_reduce_sum(s2, red);
  float r3 = block_reduce_sum(s3, red);
  if (t == 0) {
    lrv[n] = sigmoid_f(r0 + blr[0]);
    momv[n] = sigmoid_f(r1 + bmom[0]);
    decv[n] = sigmoid_f(r2 + bdec[0]);
    og[n] = sigmoid_f(r3 + bgate[0]);
  }
}

__global__ void chunk_means_k(const float* __restrict__ lrv, const float* __restrict__ momv,
                              const float* __restrict__ decv, float* __restrict__ cp) {
  int c = blockIdx.x, t = threadIdx.x;  // 64 threads
  int n = ((t >> 5) << 10) + c * 32 + (t & 31);
  float a = lrv[n], b = momv[n], d = decv[n];
  for (int off = 32; off > 0; off >>= 1) {
    a += __shfl_down(a, off);
    b += __shfl_down(b, off);
    d += __shfl_down(d, off);
  }
  if (t == 0) {
    cp[c * 3 + 0] = a * (1.f / 64.f);
    cp[c * 3 + 1] = b * (1.f / 64.f);
    cp[c * 3 + 2] = d * (1.f / 64.f);
  }
}

__global__ __launch_bounds__(256) void sampnorm2_k(const us* __restrict__ kp_b,
                                                   const float* __restrict__ dh,
                                                   const us* __restrict__ hab,
                                                   const us* __restrict__ pr,
                                                   float* __restrict__ w0inv,
                                                   float* __restrict__ w1inv, int c) {
  __shared__ float red[256];
  int i = blockIdx.x, t = threadIdx.x;
  int row = c * 64 + i;
  float sk = 0.f, sr = 0.f, sdh = 0.f, sa = 0.f;
  for (int p = t; p < 1024; p += 256) {
    float v = bf2f(kp_b[(size_t)row * 1024 + p]); sk += v * v;
    v = bf2f(pr[(size_t)(64 + i) * 1024 + p]); sr += v * v;
  }
  for (int h = t; h < 2048; h += 256) {
    float v = dh[(size_t)i * 2048 + h]; sdh += v * v;
    v = bf2f(hab[(size_t)(64 + i) * 2048 + h]); sa += v * v;
  }
  float tk = block_reduce_sum(sk, red);
  float tdh = block_reduce_sum(sdh, red);
  float ta = block_reduce_sum(sa, red);
  float tr = block_reduce_sum(sr, red);
  if (t == 0) {
    float n0 = fmaxf(sqrtf(tk) * sqrtf(tdh), 1e-8f);
    w0inv[i] = 1.0f / (64.0f * fmaxf(n0 * 0.1f, 1.0f));
    float n1 = fmaxf(sqrtf(ta) * sqrtf(tr), 1e-8f);
    w1inv[i] = 1.0f / (64.0f * fmaxf(n1 * 0.1f, 1.0f));
  }
}

// reduce 512 partials per z -> inv[z]
__global__ __launch_bounds__(512) void frob_fin512_k(const float* __restrict__ parts2,
                                                     float* __restrict__ inv) {
  __shared__ float red[512];
  int z = blockIdx.x;
  float r = block_reduce_sum(parts2[z * 512 + threadIdx.x], red);
  if (threadIdx.x == 0) inv[z] = 1.0f / (sqrtf(r) + 1e-7f);
}

// ---- merged wupd0+wupd1: grid (64,32,2) ----
__global__ void wupd01_k(float* __restrict__ W0, const us* __restrict__ X0,
                         us* __restrict__ W0bT,
                         float* __restrict__ W1, const us* __restrict__ X2,
                         us* __restrict__ W1b, us* __restrict__ W1bT,
                         const float* __restrict__ cp, int c) {
  __shared__ float tA[32][33];
  __shared__ float tB[32][33];
  float lr = cp[c * 3 + 0], om = 1.0f - cp[c * 3 + 2];
  int tx = threadIdx.x, ty = threadIdx.y;
  if (blockIdx.z == 0) {
    int c0 = blockIdx.x * 32, r0 = blockIdx.y * 32;
#pragma unroll
    for (int j = 0; j < 4; ++j) {
      int r = r0 + ty + 8 * j, h = c0 + tx;
      size_t idx = (size_t)r * 2048 + h;
      float v = om * W0[idx] + lr * bf2f(X0[idx]);
      W0[idx] = v;
      tA[ty + 8 * j][tx] = v;
    }
    __syncthreads();
#pragma unroll
    for (int j = 0; j < 4; ++j)
      W0bT[(size_t)(c0 + ty + 8 * j) * 1024 + r0 + tx] = f2bf(tA[tx][ty + 8 * j]);
  } else {
    int h0 = blockIdx.x * 32, p0 = blockIdx.y * 32;
#pragma unroll
    for (int j = 0; j < 4; ++j)
      tA[ty + 8 * j][tx] = bf2f(X2[(size_t)(p0 + ty + 8 * j) * 2048 + h0 + tx]);
    __syncthreads();
#pragma unroll
    for (int j = 0; j < 4; ++j) {
      int h = h0 + ty + 8 * j, p = p0 + tx;
      size_t idx = (size_t)h * 1024 + p;
      float v = om * W1[idx] + lr * tA[tx][ty + 8 * j];
      W1[idx] = v;
      W1b[idx] = f2bf(v);
      tB[tx][ty + 8 * j] = v;
    }
    __syncthreads();
#pragma unroll
    for (int j = 0; j < 4; ++j)
      W1bT[(size_t)(p0 + ty + 8 * j) * 2048 + h0 + tx] = f2bf(tB[ty + 8 * j][tx]);
  }
}

// ---------------- host ----------------

extern "C" void kernel_launch(void* const* d_in, const int* in_sizes, int n_in,
                              void* d_out, int out_size, void* d_ws, size_t ws_size,
                              hipStream_t stream) {
  const float* x = (const float*)d_in[0];
  const float* Wk = (const float*)d_in[1];
  const float* Wv = (const float*)d_in[2];
  const float* Wq = (const float*)d_in[3];
  const float* Wout = (const float*)d_in[4];
  const float* w_lr = (const float*)d_in[5];
  const float* b_lr = (const float*)d_in[6];
  const float* w_mom = (const float*)d_in[7];
  const float* b_mom = (const float*)d_in[8];
  const float* w_dec = (const float*)d_in[9];
  const float* b_dec = (const float*)d_in[10];
  const float* w_gate = (const float*)d_in[11];
  const float* b_gate = (const float*)d_in[12];
  const float* Wmem0 = (const float*)d_in[13];
  const float* Wmem1 = (const float*)d_in[14];
  const float* Wmemout = (const float*)d_in[15];
  const float* Wvexp = (const float*)d_in[16];
  float* out = (float*)d_out;
  (void)n_in; (void)in_sizes; (void)out_size;

  const long F = 1048576;
  const long BIG = 2097152;
  const long SB2 = 2097152, SB1 = 1048576;
  float* ws = (float*)d_ws;
  if (ws_size < (size_t)25043464 * sizeof(float)) return;

  us* kp_b   = (us*)ws;               // [0,1F)
  us* qp_b   = (us*)(ws + F);         // [1,2)
  float* vexp = ws + 2 * F;           // [2,4)
  float* W0  = ws + 4 * F;            // [4,6)
  float* W1  = ws + 6 * F;            // [6,8)
  float* S0  = ws + 8 * F;            // [8,10)
  float* S1  = ws + 10 * F;           // [10,12)
  us* XPong  = (us*)(ws + 12 * F);    // [12,14) pong packed X | Xfin rm | xb
  us* XTPong = (us*)(ws + 14 * F);    // [14,16) pong packed XT | Wkb/Wqb/Wvb
  us* XPing  = (us*)(ws + 16 * F);    // [16,18) ping packed X | vlin/WvexpT
  us* AP     = (us*)(ws + 18 * F);    // [18,19) packed A | Woutb (final)
  float* SCR = ws + 19 * F;           // [19,20) chunk scratch
  us* XTPing = (us*)(ws + 20 * F);    // [20,22) ping packed XT (= W0bT/W1bT)
  us* BP     = (us*)(ws + 22 * F);    // [22,23) packed B (= W1b)
  us* W0bT   = (us*)(ws + 20 * F);    // chunk-path alias (regenerated by wupd)
  us* W1bT   = (us*)(ws + 21 * F);
  us* W1b    = (us*)(ws + 22 * F);
  us* WmoT   = (us*)(ws + 23 * F);    // [23,23.25)
  us* retrv  = (us*)(ws + 23 * F + 262144);
  float* smal = ws + 23 * F + 262144 + 524288;
  float* og   = smal;
  float* lrv  = og + 2048;
  float* momv = lrv + 2048;
  float* decv = momv + 2048;
  float* cpb  = decv + 2048;
  float* w0inv = cpb + 128;
  float* w1inv = w0inv + 64;
  float* parts2 = w1inv + 64;         // 1024 (mg2 per-block ssq)
  float* inv01 = parts2 + 1024;

  us* xb   = XPong;                    // prologue aliases
  us* Wkb  = XTPong;
  us* Wqb  = XTPong + 1048576;
  us* Wvb  = XTPong + 2097152;
  us* vlin = XPing;
  us* WvexpT = XPing + 1048576;
  us* Woutb = AP;
  float* lin = SCR;
  us* hab   = (us*)SCR;
  float* gp = SCR + 131072;
  us* pr    = (us*)(SCR + 262144);
  float* dh = SCR + 327680;
  us* dhT   = (us*)(SCR + 458752);
  us* rbwT  = (us*)(SCR + 524288);
  us* Xfin  = XPong;                   // final NS output rm [2][1024][2048]

  const float NSa = 3.4445f, NSb = -4.7750f, NSc = 2.0315f;

  hipMemcpyAsync(W0, Wmem0, (size_t)BIG * 4, hipMemcpyDeviceToDevice, stream);
  hipMemcpyAsync(W1, Wmem1, (size_t)BIG * 4, hipMemcpyDeviceToDevice, stream);
  hipMemsetAsync(S0, 0, (size_t)BIG * 4, stream);
  hipMemsetAsync(S1, 0, (size_t)BIG * 4, stream);
  hipLaunchKernelGGL(tconv_k, dim3(64, 32), dim3(32, 8), 0, stream, Wmem0, W0bT, 1024, 2048);
  hipLaunchKernelGGL(conv_k, dim3(1024), dim3(256), 0, stream, Wmem1, W1b, (int)BIG);
  hipLaunchKernelGGL(tconv_k, dim3(32, 64), dim3(32, 8), 0, stream, Wmem1, W1bT, 2048, 1024);
  hipLaunchKernelGGL(tconv_k, dim3(16, 32), dim3(32, 8), 0, stream, Wmemout, WmoT, 1024, 512);
  hipLaunchKernelGGL(tconv_k, dim3(32, 16), dim3(32, 8), 0, stream, Wvexp, WvexpT, 512, 1024);
  hipLaunchKernelGGL(conv_k, dim3(2048), dim3(256), 0, stream, x, xb, 2048 * 2048);
  hipLaunchKernelGGL(conv_k, dim3(512), dim3(256), 0, stream, Wk, Wkb, 512 * 2048);
  hipLaunchKernelGGL(conv_k, dim3(512), dim3(256), 0, stream, Wq, Wqb, 512 * 2048);
  hipLaunchKernelGGL(conv_k, dim3(512), dim3(256), 0, stream, Wv, Wvb, 512 * 2048);

  mg<7>(stream, xb, nullptr, Wkb, lin, nullptr, nullptr, nullptr, nullptr, nullptr, 0,
        2048, 512, 2048, 2048, 2048, 512, 0);
  hipLaunchKernelGGL(polynorm2_k, dim3(2048), dim3(256), 0, stream, lin, kp_b);
  mg<7>(stream, xb, nullptr, Wqb, lin, nullptr, nullptr, nullptr, nullptr, nullptr, 0,
        2048, 512, 2048, 2048, 2048, 512, 0);
  hipLaunchKernelGGL(polynorm2_k, dim3(2048), dim3(256), 0, stream, lin, qp_b);
  mg<5>(stream, xb, nullptr, Wvb, vlin, nullptr, nullptr, nullptr, nullptr, nullptr, 0,
        2048, 512, 2048, 2048, 2048, 512, 0);
  mg<17>(stream, vlin, nullptr, WvexpT, vexp, nullptr, nullptr, nullptr, nullptr, nullptr, 0,
         2048, 1024, 512, 512, 512, 1024, 0);

  hipLaunchKernelGGL(gates_k, dim3(2048), dim3(256), 0, stream, x,
                     w_lr, b_lr, w_mom, b_mom, w_dec, b_dec, w_gate, b_gate,
                     lrv, momv, decv, og);
  hipLaunchKernelGGL(chunk_means_k, dim3(32), dim3(64), 0, stream, lrv, momv, decv, cpb);

  for (int c = 0; c < 32; ++c) {
    const us* kp_c = kp_b + (size_t)c * 64 * 1024;
    const us* qp_c = qp_b + (size_t)c * 64 * 1024;
    const float* vexp_c = vexp + (size_t)c * 64 * 1024;
    mg<8, 0, 1>(stream, qp_c, kp_c, W0bT, hab, gp, nullptr, nullptr, nullptr, nullptr, 0,
                128, 2048, 1024, 1024, 1024, 2048, 0);
    mg<9>(stream, hab, nullptr, W1bT, pr, nullptr, vexp_c, nullptr, nullptr, nullptr, 0,
          128, 1024, 2048, 2048, 2048, 1024, 1024);
    hipLaunchKernelGGL(mg34_k, dim3(40), dim3(64), 0, stream,
                       pr, WmoT, retrv + (size_t)c * 64 * 512, W1b, dh, gp);
    hipLaunchKernelGGL(sampnorm2_k, dim3(64), dim3(256), 0, stream,
                       kp_b, dh, hab, pr, w0inv, w1inv, c);
    hipLaunchKernelGGL(wt2_k, dim3(192), dim3(32, 8), 0, stream,
                       dh, w0inv, dhT, pr + 64 * 1024, w1inv, rbwT);
    hipLaunchKernelGGL(mg2_k, dim3(1024), dim3(64), 0, stream,
                       kp_c, dhT, S0, hab + 64 * 2048, rbwT, S1, cpb, c, parts2);
    hipLaunchKernelGGL(frob_fin512_k, dim3(2), dim3(512), 0, stream, parts2, inv01);
    hipLaunchKernelGGL(scalepk2_k, dim3(64, 32, 2), dim3(32, 8), 0, stream,
                       S0, S1, inv01, XPing, XTPing);

    us* xpA[2] = {XPing, XPong};
    us* xtA[2] = {XTPing, XTPong};
    int cur = 0;
    for (int it = 0; it < 5; ++it) {
      const us* XPc = xpA[cur];
      const us* XTPc = xtA[cur];
      int nxt = cur ^ 1;
      // AP = pack(Xc @ Xc^T)  (full 8x8 tile grid, K=2048)
      mgp<20, 8, 8>(stream, XPc, XPc, AP, nullptr, nullptr, 2048, 1024,
                    0.f, 0.f, SB2, SB2, SB1, 0);
      // BP = pack(NSc*(A@A) + NSb*A)  (K=1024)
      mgp<21, 8, 8>(stream, AP, AP, BP, nullptr, AP, 1024, 1024,
                    NSc, NSb, SB1, SB1, SB1, SB1);
      if (it < 4) {
        mgp<23, 8, 16>(stream, BP, XTPc, xpA[nxt], xtA[nxt], XPc, 1024, 2048,
                       NSa, 0.f, SB1, SB2, SB2, SB2);
        cur = nxt;
      } else {
        mgp<24, 8, 16>(stream, BP, XTPc, Xfin, nullptr, XPc, 1024, 2048,
                       NSa, 0.f, SB1, SB2, SB2, SB2);
      }
    }
    hipLaunchKernelGGL(wupd01_k, dim3(64, 32, 2), dim3(32, 8), 0, stream,
                       W0, Xfin, W0bT, W1, Xfin + SB2, W1b, W1bT, cpb, c);
  }

  hipLaunchKernelGGL(conv_k, dim3(1024), dim3(256), 0, stream, Wout, Woutb, 2048 * 512);
  mg<15, 0, 0, 1>(stream, retrv, nullptr, Woutb, out, nullptr, nullptr, x, og, nullptr, 0,
                  2048, 2048, 512, 512, 512, 2048, 0);
}